// Round 13
// baseline (1909.231 us; speedup 1.0000x reference)
//
#include <hip/hip_runtime.h>
#include <stdint.h>

typedef float f32x4 __attribute__((ext_vector_type(4)));
typedef short s16x8 __attribute__((ext_vector_type(8)));
typedef short s16x4 __attribute__((ext_vector_type(4)));
typedef uint32_t u32x4 __attribute__((ext_vector_type(4)));

#define HDIM 128
#define TLEN 512
#define BT 16

__device__ __forceinline__ unsigned short f2bf(float f) {
    union { float f; uint32_t u; } v; v.f = f;
    uint32_t r = v.u + 0x7FFFu + ((v.u >> 16) & 1u);
    return (unsigned short)(r >> 16);
}
__device__ __forceinline__ float bfhi(uint32_t u){ union{uint32_t u;float f;}v; v.u = u & 0xFFFF0000u; return v.f; }
__device__ __forceinline__ float bflo(uint32_t u){ union{uint32_t u;float f;}v; v.u = u << 16; return v.f; }
__device__ __forceinline__ float bf2f(short s){ union{uint32_t u;float f;}v; v.u = ((uint32_t)(unsigned short)s) << 16; return v.f; }

__device__ __forceinline__ float sigmoidf_(float x){
    float e = __expf(-x);
    return __builtin_amdgcn_rcpf(1.0f + e);
}
__device__ __forceinline__ float tanhf_(float x){
    float e = __expf(2.0f * x);
    return 1.0f - 2.0f * __builtin_amdgcn_rcpf(1.0f + e);
}

#define MFMA16(A, B, C) __builtin_amdgcn_mfma_f32_16x16x32_bf16((A), (B), (C), 0, 0, 0)

// ============================================================================
// Pack kernel: Wih1 (f32, 512x128) -> bf16 fragment-ordered in d_ws.
// Fragment F(wl,c,t) = (wl*4+c)*4+t ; lane l ; shorts at (F*64+l)*8.
// ============================================================================
__global__ __launch_bounds__(1024) void pack_wih1_kernel(
    const float* __restrict__ Wih1, short* __restrict__ dst)
{
    const int s2 = blockIdx.x * 1024 + threadIdx.x;   // 0..8191
    const int ll = s2 & 63;
    const int t  = (s2 >> 6) & 3;
    const int c  = (s2 >> 8) & 3;
    const int wl = s2 >> 10;
    const float* p = Wih1 + (t * 128 + wl * 16 + (ll & 15)) * HDIM + c * 32 + (ll >> 4) * 8;
    s16x8 a;
    #pragma unroll
    for (int j = 0; j < 8; ++j) a[j] = (short)f2bf(p[j]);
    *(s16x8*)&dst[s2 * 8] = a;
}

// ============================================================================
// Main: 128 blocks x 1024 threads (16 waves, EXACTLY 4 waves/EU -> 128-reg
// budget). L0 (w<8): Whh0 in regs/AGPRs. L1 (w>=8): Whh1 in regs/AGPRs,
// Wih1 streamed from L2 (packed ws). Zero weight-LDS streaming. Biases in
// registers. 1 barrier/step.
// ============================================================================
__global__ __launch_bounds__(1024)
__attribute__((amdgpu_waves_per_eu(4, 4)))
void lstm_mega_kernel(
    const float* __restrict__ x,
    const float* __restrict__ Wih0,
    const float* __restrict__ Whh0,
    const float* __restrict__ bih0,
    const float* __restrict__ bhh0,
    const float* __restrict__ Whh1,
    const float* __restrict__ bih1,
    const float* __restrict__ bhh1,
    const float* __restrict__ W1,
    const float* __restrict__ b1,
    const float* __restrict__ W2,
    const float* __restrict__ b2,
    const short* __restrict__ wih1pk,   // packed bf16 fragments in ws
    float* __restrict__ out)
{
    __shared__ __align__(16) short h0f[2][2048];        // 8 KB
    __shared__ __align__(16) short h1f[2][2048];        // 8 KB
    __shared__ __align__(16) float headH[16 * HDIM];    // 8 KB
    __shared__ __align__(16) float headL[16 * 64];      // 4 KB

    const int tid = threadIdx.x;
    const int w   = tid >> 6;        // 0..15
    const int wl  = w & 7;           // wave-in-team; owns units [16wl,16wl+16)
    const bool isL0 = (w < 8);
    const int l = tid & 63;
    const int n = l & 15;            // batch col
    const int q = l >> 4;            // k-group / row-quad
    const int b0 = blockIdx.x * BT;
    const float* xrow = x + (size_t)(b0 + n) * TLEN;

    // zero h1[-1] (read at k=0 from h1f[1]): 1024 u32, one per thread
    ((uint32_t*)h1f[1])[tid] = 0u;

    // B-fragment write slot for this lane's 4 units
    const int u0 = wl * 16 + q * 4;
    const int fragoff = ((u0 >> 5) * 64 + n + 16 * ((u0 >> 3) & 3)) * 8 + (u0 & 7);

#define L0ITER(K, R, W) do {                                                  \
    const int xi_ = (K) + 1;                                                  \
    const float xv_ = xrow[xi_ < TLEN ? xi_ : (TLEN - 1)];                    \
    s16x8 hb_[4];                                                             \
    _Pragma("unroll")                                                         \
    for (int c = 0; c < 4; ++c) hb_[c] = *(const s16x8*)&(R)[(c * 64 + l) * 8]; \
    f32x4 acc_[4];                                                            \
    _Pragma("unroll")                                                         \
    for (int t = 0; t < 4; ++t) {                                             \
        _Pragma("unroll")                                                     \
        for (int r = 0; r < 4; ++r)                                           \
            acc_[t][r] = fmaf(bfhi(bwx[t][r]), xv_, bflo(bwx[t][r]));         \
    }                                                                         \
    _Pragma("unroll")                                                         \
    for (int c = 0; c < 4; ++c) {                                             \
        _Pragma("unroll")                                                     \
        for (int t = 0; t < 4; ++t)                                           \
            acc_[t] = MFMA16(w0f[c][t], hb_[c], acc_[t]);                     \
    }                                                                         \
    s16x4 hw_;                                                                \
    _Pragma("unroll")                                                         \
    for (int r = 0; r < 4; ++r) {                                             \
        const float ig = sigmoidf_(acc_[0][r]);                               \
        const float fg = sigmoidf_(acc_[1][r]);                               \
        const float gg = tanhf_(acc_[2][r]);                                  \
        const float og = sigmoidf_(acc_[3][r]);                               \
        const float cc = fmaf(fg, c0v[r], ig * gg);                           \
        c0v[r] = cc;                                                          \
        hw_[r] = (short)f2bf(og * tanhf_(cc));                                \
    }                                                                         \
    *(s16x4*)&(W)[fragoff] = hw_;                                             \
    __syncthreads();                                                          \
} while (0)

// L1: Whh1 in regs/AGPRs (wh1f), Wih1 streamed 2-deep from L2 (low reg peak)
#define L1ITER(K, R0, R1, W1B) do {                                           \
    f32x4 acc_[4];                                                            \
    _Pragma("unroll")                                                         \
    for (int t = 0; t < 4; ++t) acc_[t] = b1r[t];                             \
    _Pragma("unroll")                                                         \
    for (int c = 0; c < 4; ++c) {                                             \
        const s16x8 hb0_ = *(const s16x8*)&(R0)[(c * 64 + l) * 8];            \
        const s16x8 hb1_ = *(const s16x8*)&(R1)[(c * 64 + l) * 8];            \
        s16x8 wiA_ = *(const s16x8*)&wih1pk[(((wl * 4 + c) * 4 + 0) * 64 + l) * 8]; \
        s16x8 wiB_ = *(const s16x8*)&wih1pk[(((wl * 4 + c) * 4 + 1) * 64 + l) * 8]; \
        acc_[0] = MFMA16(wh1f[c][0], hb1_, acc_[0]);                          \
        acc_[1] = MFMA16(wh1f[c][1], hb1_, acc_[1]);                          \
        acc_[0] = MFMA16(wiA_, hb0_, acc_[0]);                                \
        acc_[1] = MFMA16(wiB_, hb0_, acc_[1]);                                \
        wiA_ = *(const s16x8*)&wih1pk[(((wl * 4 + c) * 4 + 2) * 64 + l) * 8]; \
        wiB_ = *(const s16x8*)&wih1pk[(((wl * 4 + c) * 4 + 3) * 64 + l) * 8]; \
        acc_[2] = MFMA16(wh1f[c][2], hb1_, acc_[2]);                          \
        acc_[3] = MFMA16(wh1f[c][3], hb1_, acc_[3]);                          \
        acc_[2] = MFMA16(wiA_, hb0_, acc_[2]);                                \
        acc_[3] = MFMA16(wiB_, hb0_, acc_[3]);                                \
    }                                                                         \
    s16x4 hw_;                                                                \
    _Pragma("unroll")                                                         \
    for (int r = 0; r < 4; ++r) {                                             \
        const float ig = sigmoidf_(acc_[0][r]);                               \
        const float fg = sigmoidf_(acc_[1][r]);                               \
        const float gg = tanhf_(acc_[2][r]);                                  \
        const float og = sigmoidf_(acc_[3][r]);                               \
        const float cc = fmaf(fg, c1v[r], ig * gg);                           \
        c1v[r] = cc;                                                          \
        hw_[r] = (short)f2bf(og * tanhf_(cc));                                \
    }                                                                         \
    *(s16x4*)&(W1B)[fragoff] = hw_;                                           \
    __syncthreads();                                                          \
} while (0)

    if (isL0) {
        // ---- L0 wave: Whh0 fragments (64 regs, MFMA-A -> AGPR) ----
        s16x8 w0f[4][4];   // [c][t]
        #pragma unroll
        for (int c = 0; c < 4; ++c) {
            #pragma unroll
            for (int t = 0; t < 4; ++t) {
                const float* p = Whh0 + (t * 128 + wl * 16 + n) * HDIM + c * 32 + q * 8;
                s16x8 a;
                #pragma unroll
                for (int j = 0; j < 8; ++j) a[j] = (short)f2bf(p[j]);
                w0f[c][t] = a;
            }
        }
        // packed (wx, bias0) per owned gate-row quad (16 regs)
        u32x4 bwx[4];
        #pragma unroll
        for (int t = 0; t < 4; ++t) {
            #pragma unroll
            for (int r = 0; r < 4; ++r) {
                const int row = t * 128 + wl * 16 + q * 4 + r;
                bwx[t][r] = ((uint32_t)f2bf(Wih0[row]) << 16) | f2bf(bih0[row] + bhh0[row]);
            }
        }
        float c0v[4] = {0.f, 0.f, 0.f, 0.f};

        __syncthreads();   // h1f[1] zero visible

        // prologue: h0[0] = pointwise(b0 + wx*x[0]) ; h0[-1]=0 so no MFMA
        {
            const float x0 = xrow[0];
            s16x4 hw;
            #pragma unroll
            for (int r = 0; r < 4; ++r) {
                const float pi = fmaf(bfhi(bwx[0][r]), x0, bflo(bwx[0][r]));
                const float pg = fmaf(bfhi(bwx[2][r]), x0, bflo(bwx[2][r]));
                const float po = fmaf(bfhi(bwx[3][r]), x0, bflo(bwx[3][r]));
                const float ig = sigmoidf_(pi);
                const float gg = tanhf_(pg);
                const float og = sigmoidf_(po);
                const float cc = ig * gg;          // f * c(-1) = 0
                c0v[r] = cc;
                hw[r] = (short)f2bf(og * tanhf_(cc));
            }
            *(s16x4*)&h0f[0][fragoff] = hw;
        }
        __syncthreads();   // h0[0] visible

        #pragma unroll 1
        for (int k = 0; k < TLEN; k += 2) {
            L0ITER(k,     h0f[0], h0f[1]);
            L0ITER(k + 1, h0f[1], h0f[0]);
        }
    } else {
        // ---- L1 wave: Whh1 fragments (64 regs, MFMA-A -> AGPR) ----
        s16x8 wh1f[4][4];   // [c][t]
        #pragma unroll
        for (int c = 0; c < 4; ++c) {
            #pragma unroll
            for (int t = 0; t < 4; ++t) {
                const float* p = Whh1 + (t * 128 + wl * 16 + n) * HDIM + c * 32 + q * 8;
                s16x8 a;
                #pragma unroll
                for (int j = 0; j < 8; ++j) a[j] = (short)f2bf(p[j]);
                wh1f[c][t] = a;
            }
        }
        // bias1 per owned gate-row quad (16 regs)
        f32x4 b1r[4];
        #pragma unroll
        for (int t = 0; t < 4; ++t) {
            #pragma unroll
            for (int r = 0; r < 4; ++r) {
                const int row = t * 128 + wl * 16 + q * 4 + r;
                b1r[t][r] = bih1[row] + bhh1[row];
            }
        }
        float c1v[4] = {0.f, 0.f, 0.f, 0.f};

        __syncthreads();   // pairs with L0 post-staging barrier
        __syncthreads();   // pairs with L0 post-prologue barrier

        #pragma unroll 1
        for (int k = 0; k < TLEN; k += 2) {
            L1ITER(k,     h0f[0], h1f[1], h1f[0]);
            L1ITER(k + 1, h0f[1], h1f[0], h1f[1]);
        }
        // h1[511] now in h1f[1]
    }

    // ---- head ----
    if (!isL0) {
        const s16x4 hv = *(const s16x4*)&h1f[1][fragoff];
        f32x4 hf;
        #pragma unroll
        for (int r = 0; r < 4; ++r) hf[r] = bf2f(hv[r]);
        *(f32x4*)&headH[n * HDIM + u0] = hf;
    }
    __syncthreads();

    {   // hidden = relu(h @ W1^T + b1): 1024 threads = 16 batch x 64 hidden
        const int nn = tid >> 6, j = tid & 63;
        float s = b1[j];
        const float* wrow = W1 + j * HDIM;
        const float* hrow = headH + nn * HDIM;
        #pragma unroll
        for (int k = 0; k < HDIM; k += 4) {
            const f32x4 hv = *(const f32x4*)&hrow[k];
            const f32x4 wv = *(const f32x4*)&wrow[k];
            s += hv[0]*wv[0] + hv[1]*wv[1] + hv[2]*wv[2] + hv[3]*wv[3];
        }
        headL[nn * 64 + j] = fmaxf(s, 0.0f);
    }
    __syncthreads();

    if (tid < 128) {
        const int nn = tid >> 3, cls = tid & 7;
        float s = b2[cls];
        const float* wrow = W2 + cls * 64;
        const float* hrow = headL + nn * 64;
        #pragma unroll
        for (int k = 0; k < 64; k += 4) {
            const f32x4 hv = *(const f32x4*)&hrow[k];
            const f32x4 wv = *(const f32x4*)&wrow[k];
            s += hv[0]*wv[0] + hv[1]*wv[1] + hv[2]*wv[2] + hv[3]*wv[3];
        }
        out[(size_t)(b0 + nn) * 8 + cls] = s;
    }
#undef L0ITER
#undef L1ITER
}

// ============================================================================
// Fallback (round-6 kernel, 954 us): used when ws_size < 128 KB.
// ============================================================================
__global__ __launch_bounds__(512, 2) void lstm_fused_kernel(
    const float* __restrict__ x,
    const float* __restrict__ Wih0,
    const float* __restrict__ Whh0,
    const float* __restrict__ bih0,
    const float* __restrict__ bhh0,
    const float* __restrict__ Wih1,
    const float* __restrict__ Whh1,
    const float* __restrict__ bih1,
    const float* __restrict__ bhh1,
    const float* __restrict__ W1,
    const float* __restrict__ b1,
    const float* __restrict__ W2,
    const float* __restrict__ b2,
    float* __restrict__ out)
{
    __shared__ __align__(16) short wh1lds[65536];
    __shared__ __align__(16) short h0f0[2048], h0f1[2048];
    __shared__ __align__(16) short h1f0[2048], h1f1[2048];
    __shared__ __align__(16) float b1lds[4][8][16];

    const int tid = threadIdx.x;
    const int w   = tid >> 6;
    const int wl  = w & 3;
    const bool isL0 = (w < 4);
    const int l = tid & 63;
    const int n = l & 15;
    const int q = l >> 4;
    const int b0 = blockIdx.x * BT;
    const float* xrow = x + (size_t)(b0 + n) * TLEN;

    for (int s2 = tid; s2 < 8192; s2 += 512) {
        const int ll = s2 & 63, t2 = (s2 >> 6) & 7, cc = (s2 >> 9) & 3, wv = s2 >> 11;
        const int row = (t2 >> 1) * 128 + 32 * wv + 16 * (t2 & 1) + (ll & 15);
        const int k0  = cc * 32 + (ll >> 4) * 8;
        const float* p = Whh1 + row * HDIM + k0;
        s16x8 a;
        #pragma unroll
        for (int j = 0; j < 8; ++j) a[j] = (short)f2bf(p[j]);
        *(s16x8*)&wh1lds[s2 * 8] = a;
    }
    {
        const int idx = tid;
        const int wv = idx >> 7, t2 = (idx >> 4) & 7, j = idx & 15;
        const int row = (t2 >> 1) * 128 + 32 * wv + 16 * (t2 & 1) + j;
        b1lds[wv][t2][j] = bih1[row] + bhh1[row];
    }
    for (int s2 = tid; s2 < 1024; s2 += 512) ((uint32_t*)h1f1)[s2] = 0u;

    const int ub0 = 32 * wl + 4 * q;
    const int ub1 = ub0 + 16;
    const int fo0 = ((ub0 >> 5) * 64 + n + 16 * ((ub0 >> 3) & 3)) * 8 + (ub0 & 7);
    const int fo1 = ((ub1 >> 5) * 64 + n + 16 * ((ub1 >> 3) & 3)) * 8 + (ub1 & 7);

#define L0ITER(K, R0, W0) do {                                                \
    const int xi_ = (K) + 1;                                                  \
    const float xv_ = xrow[xi_ < TLEN ? xi_ : (TLEN - 1)];                    \
    s16x8 hb_[4];                                                             \
    _Pragma("unroll")                                                         \
    for (int c = 0; c < 4; ++c) hb_[c] = *(const s16x8*)&(R0)[(c * 64 + l) * 8]; \
    f32x4 a_[8];                                                              \
    _Pragma("unroll")                                                         \
    for (int t2 = 0; t2 < 8; ++t2) {                                          \
        _Pragma("unroll")                                                     \
        for (int r = 0; r < 4; ++r)                                           \
            a_[t2][r] = fmaf(bfhi(bwx[t2][r]), xv_, bflo(bwx[t2][r]));        \
    }                                                                         \
    _Pragma("unroll")                                                         \
    for (int c = 0; c < 4; ++c) {                                             \
        _Pragma("unroll")                                                     \
        for (int t2 = 0; t2 < 8; ++t2)                                        \
            a_[t2] = MFMA16(w0f[c][t2], hb_[c], a_[t2]);                      \
    }                                                                         \
    _Pragma("unroll")                                                         \
    for (int h = 0; h < 2; ++h) {                                             \
        s16x4 hw;                                                             \
        _Pragma("unroll")                                                     \
        for (int r = 0; r < 4; ++r) {                                         \
            const float ig = sigmoidf_(a_[0 + h][r]);                         \
            const float fg = sigmoidf_(a_[2 + h][r]);                         \
            const float gg = tanhf_(a_[4 + h][r]);                            \
            const float og = sigmoidf_(a_[6 + h][r]);                         \
            const float cc = fmaf(fg, c0_[h][r], ig * gg);                    \
            c0_[h][r] = cc;                                                   \
            hw[r] = (short)f2bf(og * tanhf_(cc));                             \
        }                                                                     \
        *(s16x4*)&(W0)[h ? fo1 : fo0] = hw;                                   \
    }                                                                         \
    __syncthreads();                                                          \
} while (0)

#define L1ITER(K, R0, R1, W1) do {                                            \
    s16x8 hb0_[4], hb1_[4];                                                   \
    _Pragma("unroll")                                                         \
    for (int c = 0; c < 4; ++c) {                                             \
        hb0_[c] = *(const s16x8*)&(R0)[(c * 64 + l) * 8];                     \
        hb1_[c] = *(const s16x8*)&(R1)[(c * 64 + l) * 8];                     \
    }                                                                         \
    f32x4 a_[8];                                                              \
    _Pragma("unroll")                                                         \
    for (int t2 = 0; t2 < 8; ++t2)                                            \
        a_[t2] = *(const f32x4*)&b1lds[wl][t2][q * 4];                        \
    _Pragma("unroll")                                                         \
    for (int c = 0; c < 4; ++c) {                                             \
        _Pragma("unroll")                                                     \
        for (int t2 = 0; t2 < 8; ++t2)                                        \
            a_[t2] = MFMA16(wi1f[c][t2], hb0_[c], a_[t2]);                    \
    }                                                                         \
    _Pragma("unroll")                                                         \
    for (int c = 0; c < 4; ++c) {                                             \
        s16x8 wt_[8];                                                         \
        _Pragma("unroll")                                                     \
        for (int t2 = 0; t2 < 8; ++t2)                                        \
            wt_[t2] = *(const s16x8*)&wh1lds[(((wl * 4 + c) * 8 + t2) * 64 + l) * 8]; \
        _Pragma("unroll")                                                     \
        for (int t2 = 0; t2 < 8; ++t2)                                        \
            a_[t2] = MFMA16(wt_[t2], hb1_[c], a_[t2]);                        \
    }                                                                         \
    _Pragma("unroll")                                                         \
    for (int h = 0; h < 2; ++h) {                                             \
        s16x4 hw;                                                             \
        _Pragma("unroll")                                                     \
        for (int r = 0; r < 4; ++r) {                                         \
            const float ig = sigmoidf_(a_[0 + h][r]);                         \
            const float fg = sigmoidf_(a_[2 + h][r]);                         \
            const float gg = tanhf_(a_[4 + h][r]);                            \
            const float og = sigmoidf_(a_[6 + h][r]);                         \
            const float cc = fmaf(fg, c1_[h][r], ig * gg);                    \
            c1_[h][r] = cc;                                                   \
            hw[r] = (short)f2bf(og * tanhf_(cc));                             \
        }                                                                     \
        *(s16x4*)&(W1)[h ? fo1 : fo0] = hw;                                   \
    }                                                                         \
    __syncthreads();                                                          \
} while (0)

    if (isL0) {
        s16x8 w0f[4][8];
        #pragma unroll
        for (int c = 0; c < 4; ++c) {
            #pragma unroll
            for (int t2 = 0; t2 < 8; ++t2) {
                const int row = (t2 >> 1) * 128 + 32 * wl + 16 * (t2 & 1) + n;
                const int k0 = c * 32 + q * 8;
                const float* p = Whh0 + row * HDIM + k0;
                s16x8 a;
                #pragma unroll
                for (int j = 0; j < 8; ++j) a[j] = (short)f2bf(p[j]);
                w0f[c][t2] = a;
            }
        }
        u32x4 bwx[8];
        #pragma unroll
        for (int t2 = 0; t2 < 8; ++t2) {
            #pragma unroll
            for (int r = 0; r < 4; ++r) {
                const int row = (t2 >> 1) * 128 + 32 * wl + 16 * (t2 & 1) + 4 * q + r;
                bwx[t2][r] = ((uint32_t)f2bf(Wih0[row]) << 16) | f2bf(bih0[row] + bhh0[row]);
            }
        }
        float c0_[2][4] = {{0.f,0.f,0.f,0.f},{0.f,0.f,0.f,0.f}};
        {
            const float x0 = xrow[0];
            #pragma unroll
            for (int h = 0; h < 2; ++h) {
                s16x4 hw;
                #pragma unroll
                for (int r = 0; r < 4; ++r) {
                    const float pi = fmaf(bfhi(bwx[0 + h][r]), x0, bflo(bwx[0 + h][r]));
                    const float pg = fmaf(bfhi(bwx[4 + h][r]), x0, bflo(bwx[4 + h][r]));
                    const float po = fmaf(bfhi(bwx[6 + h][r]), x0, bflo(bwx[6 + h][r]));
                    const float ig = sigmoidf_(pi);
                    const float gg = tanhf_(pg);
                    const float og = sigmoidf_(po);
                    const float cc = ig * gg;
                    c0_[h][r] = cc;
                    hw[r] = (short)f2bf(og * tanhf_(cc));
                }
                *(s16x4*)&h0f0[h ? fo1 : fo0] = hw;
            }
        }
        __syncthreads();
        #pragma unroll 1
        for (int k = 0; k < TLEN; k += 2) {
            L0ITER(k,     h0f0, h0f1);
            L0ITER(k + 1, h0f1, h0f0);
        }
    } else {
        s16x8 wi1f[4][8];
        #pragma unroll
        for (int c = 0; c < 4; ++c) {
            #pragma unroll
            for (int t2 = 0; t2 < 8; ++t2) {
                const int row = (t2 >> 1) * 128 + 32 * wl + 16 * (t2 & 1) + n;
                const int k0 = c * 32 + q * 8;
                const float* p = Wih1 + row * HDIM + k0;
                s16x8 a;
                #pragma unroll
                for (int j = 0; j < 8; ++j) a[j] = (short)f2bf(p[j]);
                wi1f[c][t2] = a;
            }
        }
        float c1_[2][4] = {{0.f,0.f,0.f,0.f},{0.f,0.f,0.f,0.f}};
        __syncthreads();
        #pragma unroll 1
        for (int k = 0; k < TLEN; k += 2) {
            L1ITER(k,     h0f0, h1f1, h1f0);
            L1ITER(k + 1, h0f1, h1f0, h1f1);
        }
    }

    __syncthreads();

    float* headH = (float*)wh1lds;
    float* headL = headH + 16 * HDIM;
    if (!isL0) {
        #pragma unroll
        for (int h = 0; h < 2; ++h) {
            const s16x4 hv = *(const s16x4*)&h1f1[h ? fo1 : fo0];
            f32x4 hf;
            #pragma unroll
            for (int r = 0; r < 4; ++r) hf[r] = bf2f(hv[r]);
            *(f32x4*)&headH[n * HDIM + (h ? ub1 : ub0)] = hf;
        }
    }
    __syncthreads();

    #pragma unroll
    for (int rep = 0; rep < 2; ++rep) {
        const int idx = tid + rep * 512;
        const int nn = idx >> 6, j = idx & 63;
        float s = b1[j];
        const float* wrow = W1 + j * HDIM;
        const float* hrow = headH + nn * HDIM;
        #pragma unroll
        for (int k = 0; k < HDIM; k += 4) {
            const f32x4 hv = *(const f32x4*)&hrow[k];
            const f32x4 wv = *(const f32x4*)&wrow[k];
            s += hv[0]*wv[0] + hv[1]*wv[1] + hv[2]*wv[2] + hv[3]*wv[3];
        }
        headL[nn * 64 + j] = fmaxf(s, 0.0f);
    }
    __syncthreads();

    if (tid < 128) {
        const int nn = tid >> 3, cls = tid & 7;
        float s = b2[cls];
        const float* wrow = W2 + cls * 64;
        const float* hrow = headL + nn * 64;
        #pragma unroll
        for (int k = 0; k < 64; k += 4) {
            const f32x4 hv = *(const f32x4*)&hrow[k];
            const f32x4 wv = *(const f32x4*)&wrow[k];
            s += hv[0]*wv[0] + hv[1]*wv[1] + hv[2]*wv[2] + hv[3]*wv[3];
        }
        out[(size_t)(b0 + nn) * 8 + cls] = s;
    }
#undef L0ITER
#undef L1ITER
}

extern "C" void kernel_launch(void* const* d_in, const int* in_sizes, int n_in,
                              void* d_out, int out_size, void* d_ws, size_t ws_size,
                              hipStream_t stream) {
    const float* x    = (const float*)d_in[0];
    const float* Wih0 = (const float*)d_in[1];
    const float* Whh0 = (const float*)d_in[2];
    const float* bih0 = (const float*)d_in[3];
    const float* bhh0 = (const float*)d_in[4];
    const float* Wih1 = (const float*)d_in[5];
    const float* Whh1 = (const float*)d_in[6];
    const float* bih1 = (const float*)d_in[7];
    const float* bhh1 = (const float*)d_in[8];
    const float* W1   = (const float*)d_in[9];
    const float* b1   = (const float*)d_in[10];
    const float* W2   = (const float*)d_in[11];
    const float* b2   = (const float*)d_in[12];
    float* outp = (float*)d_out;

    const size_t PACK_BYTES = (size_t)512 * 128 * sizeof(short);   // 128 KB

    if (ws_size >= PACK_BYTES) {
        short* wih1pk = (short*)d_ws;
        pack_wih1_kernel<<<8, 1024, 0, stream>>>(Wih1, wih1pk);
        lstm_mega_kernel<<<128, 1024, 0, stream>>>(
            x, Wih0, Whh0, bih0, bhh0, Whh1, bih1, bhh1,
            W1, b1, W2, b2, wih1pk, outp);
    } else {
        lstm_fused_kernel<<<128, 512, 0, stream>>>(
            x, Wih0, Whh0, bih0, bhh0, Wih1, Whh1, bih1, bhh1,
            W1, b1, W2, b2, outp);
    }
}

// Round 14
// 1434.197 us; speedup vs baseline: 1.3312x; 1.3312x over previous
//
#include <hip/hip_runtime.h>
#include <stdint.h>

typedef float f32x4 __attribute__((ext_vector_type(4)));
typedef short s16x8 __attribute__((ext_vector_type(8)));
typedef short s16x4 __attribute__((ext_vector_type(4)));
typedef uint32_t u32x4 __attribute__((ext_vector_type(4)));

#define HDIM 128
#define TLEN 512
#define BT 16

__device__ __forceinline__ unsigned short f2bf(float f) {
    union { float f; uint32_t u; } v; v.f = f;
    uint32_t r = v.u + 0x7FFFu + ((v.u >> 16) & 1u);
    return (unsigned short)(r >> 16);
}
__device__ __forceinline__ float bfhi(uint32_t u){ union{uint32_t u;float f;}v; v.u = u & 0xFFFF0000u; return v.f; }
__device__ __forceinline__ float bflo(uint32_t u){ union{uint32_t u;float f;}v; v.u = u << 16; return v.f; }
__device__ __forceinline__ float bf2f(short s){ union{uint32_t u;float f;}v; v.u = ((uint32_t)(unsigned short)s) << 16; return v.f; }

__device__ __forceinline__ float sigmoidf_(float x){
    float e = __expf(-x);
    return __builtin_amdgcn_rcpf(1.0f + e);
}
__device__ __forceinline__ float tanhf_(float x){
    float e = __expf(2.0f * x);
    return 1.0f - 2.0f * __builtin_amdgcn_rcpf(1.0f + e);
}

#define MFMA16(A, B, C) __builtin_amdgcn_mfma_f32_16x16x32_bf16((A), (B), (C), 0, 0, 0)

// ============================================================================
// Pack kernel: Wih1 (f32, 512x128) -> bf16 fragment-ordered for the round-6
// wave layout. Fragment F(wl,c,t2) = (wl*4+c)*8+t2; lane l; shorts (F*64+l)*8.
// row = (t2>>1)*128 + 32*wl + 16*(t2&1) + (l&15); col = c*32 + (l>>4)*8.
// ============================================================================
__global__ __launch_bounds__(1024) void pack_wih1_kernel(
    const float* __restrict__ Wih1, short* __restrict__ dst)
{
    const int s2 = blockIdx.x * 1024 + threadIdx.x;   // 0..8191
    const int l  = s2 & 63;
    const int t2 = (s2 >> 6) & 7;
    const int c  = (s2 >> 9) & 3;
    const int wl = (s2 >> 11) & 3;
    const int row = (t2 >> 1) * 128 + 32 * wl + 16 * (t2 & 1) + (l & 15);
    const float* p = Wih1 + row * HDIM + c * 32 + (l >> 4) * 8;
    s16x8 a;
    #pragma unroll
    for (int j = 0; j < 8; ++j) a[j] = (short)f2bf(p[j]);
    *(s16x8*)&dst[s2 * 8] = a;
}

// ============================================================================
// Main: 128 blocks x 512 threads (8 waves, 2/SIMD -> 256-reg budget).
// L0 (w<4): Whh0 in 128 acc regs (round-6 proven). L1 (w>=4): Whh1 in 128
// acc regs, Wih1 streamed from L2 (packed in ws). NO weight-LDS streaming.
// 1 barrier per team-iter.
// ============================================================================
__global__ __launch_bounds__(512, 2) void lstm_allreg_kernel(
    const float* __restrict__ x,
    const float* __restrict__ Wih0,
    const float* __restrict__ Whh0,
    const float* __restrict__ bih0,
    const float* __restrict__ bhh0,
    const float* __restrict__ Whh1,
    const float* __restrict__ bih1,
    const float* __restrict__ bhh1,
    const float* __restrict__ W1,
    const float* __restrict__ b1,
    const float* __restrict__ W2,
    const float* __restrict__ b2,
    const short* __restrict__ wih1pk,   // packed bf16 Wih1 fragments in ws
    float* __restrict__ out)
{
    __shared__ __align__(16) short h0f0[2048], h0f1[2048];   // 8 KB
    __shared__ __align__(16) short h1f0[2048], h1f1[2048];   // 8 KB
    __shared__ __align__(16) float b1lds[4][8][16];          // 2 KB
    __shared__ __align__(16) float headH[16 * HDIM];         // 8 KB
    __shared__ __align__(16) float headL[16 * 64];           // 4 KB

    const int tid = threadIdx.x;
    const int w   = tid >> 6;
    const int wl  = w & 3;          // wave-in-team; owns units [32wl, 32wl+32)
    const bool isL0 = (w < 4);
    const int l = tid & 63;
    const int n = l & 15;           // batch col
    const int q = l >> 4;           // k-group / row-quad
    const int b0 = blockIdx.x * BT;
    const float* xrow = x + (size_t)(b0 + n) * TLEN;

    // ---- b1 broadcast table (512 entries, one per thread) ----
    {
        const int wv = tid >> 7, t2 = (tid >> 4) & 7, j = tid & 15;
        const int row = (t2 >> 1) * 128 + 32 * wv + 16 * (t2 & 1) + j;
        b1lds[wv][t2][j] = bih1[row] + bhh1[row];
    }
    // zero h1[-1]
    for (int s2 = tid; s2 < 1024; s2 += 512) ((uint32_t*)h1f1)[s2] = 0u;

    // B-fragment write slots for this lane's unit quads (h=0 / h=1)
    const int ub0 = 32 * wl + 4 * q;
    const int ub1 = ub0 + 16;
    const int fo0 = ((ub0 >> 5) * 64 + n + 16 * ((ub0 >> 3) & 3)) * 8 + (ub0 & 7);
    const int fo1 = ((ub1 >> 5) * 64 + n + 16 * ((ub1 >> 3) & 3)) * 8 + (ub1 & 7);

#define L0ITER(K, R0, W0) do {                                                \
    const int xi_ = (K) + 1;                                                  \
    const float xv_ = xrow[xi_ < TLEN ? xi_ : (TLEN - 1)];                    \
    s16x8 hb_[4];                                                             \
    _Pragma("unroll")                                                         \
    for (int c = 0; c < 4; ++c) hb_[c] = *(const s16x8*)&(R0)[(c * 64 + l) * 8]; \
    f32x4 a_[8];                                                              \
    _Pragma("unroll")                                                         \
    for (int t2 = 0; t2 < 8; ++t2) {                                          \
        _Pragma("unroll")                                                     \
        for (int r = 0; r < 4; ++r)                                           \
            a_[t2][r] = fmaf(bfhi(bwx[t2][r]), xv_, bflo(bwx[t2][r]));        \
    }                                                                         \
    _Pragma("unroll")                                                         \
    for (int c = 0; c < 4; ++c) {                                             \
        _Pragma("unroll")                                                     \
        for (int t2 = 0; t2 < 8; ++t2)                                        \
            a_[t2] = MFMA16(w0f[c][t2], hb_[c], a_[t2]);                      \
    }                                                                         \
    _Pragma("unroll")                                                         \
    for (int h = 0; h < 2; ++h) {                                             \
        s16x4 hw;                                                             \
        _Pragma("unroll")                                                     \
        for (int r = 0; r < 4; ++r) {                                         \
            const float ig = sigmoidf_(a_[0 + h][r]);                         \
            const float fg = sigmoidf_(a_[2 + h][r]);                         \
            const float gg = tanhf_(a_[4 + h][r]);                            \
            const float og = sigmoidf_(a_[6 + h][r]);                         \
            const float cc = fmaf(fg, c0_[h][r], ig * gg);                    \
            c0_[h][r] = cc;                                                   \
            hw[r] = (short)f2bf(og * tanhf_(cc));                             \
        }                                                                     \
        *(s16x4*)&(W0)[h ? fo1 : fo0] = hw;                                   \
    }                                                                         \
    __syncthreads();                                                          \
} while (0)

// L1: Whh1 in acc regs (wh1f); Wih1 streamed from packed global per (h,c);
// computed in 2 halves (4 acc tiles at a time) to cap transient pressure.
#define L1ITER(K, R0, R1, W1B) do {                                           \
    s16x8 hb0_[4], hb1_[4];                                                   \
    _Pragma("unroll")                                                         \
    for (int c = 0; c < 4; ++c) {                                             \
        hb0_[c] = *(const s16x8*)&(R0)[(c * 64 + l) * 8];                     \
        hb1_[c] = *(const s16x8*)&(R1)[(c * 64 + l) * 8];                     \
    }                                                                         \
    _Pragma("unroll")                                                         \
    for (int h = 0; h < 2; ++h) {                                             \
        f32x4 a_[4];                                                          \
        _Pragma("unroll")                                                     \
        for (int g = 0; g < 4; ++g)                                           \
            a_[g] = *(const f32x4*)&b1lds[wl][2 * g + h][q * 4];              \
        _Pragma("unroll")                                                     \
        for (int c = 0; c < 4; ++c) {                                         \
            s16x8 wi0_ = *(const s16x8*)&wih1pk[(((wl * 4 + c) * 8 + 0 + h) * 64 + l) * 8]; \
            s16x8 wi1_ = *(const s16x8*)&wih1pk[(((wl * 4 + c) * 8 + 2 + h) * 64 + l) * 8]; \
            s16x8 wi2_ = *(const s16x8*)&wih1pk[(((wl * 4 + c) * 8 + 4 + h) * 64 + l) * 8]; \
            s16x8 wi3_ = *(const s16x8*)&wih1pk[(((wl * 4 + c) * 8 + 6 + h) * 64 + l) * 8]; \
            a_[0] = MFMA16(wh1f[c][0 + h], hb1_[c], a_[0]);                   \
            a_[1] = MFMA16(wh1f[c][2 + h], hb1_[c], a_[1]);                   \
            a_[2] = MFMA16(wh1f[c][4 + h], hb1_[c], a_[2]);                   \
            a_[3] = MFMA16(wh1f[c][6 + h], hb1_[c], a_[3]);                   \
            a_[0] = MFMA16(wi0_, hb0_[c], a_[0]);                             \
            a_[1] = MFMA16(wi1_, hb0_[c], a_[1]);                             \
            a_[2] = MFMA16(wi2_, hb0_[c], a_[2]);                             \
            a_[3] = MFMA16(wi3_, hb0_[c], a_[3]);                             \
        }                                                                     \
        s16x4 hw;                                                             \
        _Pragma("unroll")                                                     \
        for (int r = 0; r < 4; ++r) {                                         \
            const float ig = sigmoidf_(a_[0][r]);                             \
            const float fg = sigmoidf_(a_[1][r]);                             \
            const float gg = tanhf_(a_[2][r]);                                \
            const float og = sigmoidf_(a_[3][r]);                             \
            const float cc = fmaf(fg, c1_[h][r], ig * gg);                    \
            c1_[h][r] = cc;                                                   \
            hw[r] = (short)f2bf(og * tanhf_(cc));                             \
        }                                                                     \
        *(s16x4*)&(W1B)[h ? fo1 : fo0] = hw;                                  \
    }                                                                         \
    __syncthreads();                                                          \
} while (0)

    if (isL0) {
        // ---- L0 team: Whh0 fully in regs (128, -> acc file) ----
        s16x8 w0f[4][8];
        #pragma unroll
        for (int c = 0; c < 4; ++c) {
            #pragma unroll
            for (int t2 = 0; t2 < 8; ++t2) {
                const int row = (t2 >> 1) * 128 + 32 * wl + 16 * (t2 & 1) + n;
                const int k0 = c * 32 + q * 8;
                const float* p = Whh0 + row * HDIM + k0;
                s16x8 a;
                #pragma unroll
                for (int j = 0; j < 8; ++j) a[j] = (short)f2bf(p[j]);
                w0f[c][t2] = a;
            }
        }
        // packed (wx, bias0) per owned gate-row (32 regs)
        u32x4 bwx[8];
        #pragma unroll
        for (int t2 = 0; t2 < 8; ++t2) {
            #pragma unroll
            for (int r = 0; r < 4; ++r) {
                const int row = (t2 >> 1) * 128 + 32 * wl + 16 * (t2 & 1) + 4 * q + r;
                bwx[t2][r] = ((uint32_t)f2bf(Wih0[row]) << 16) | f2bf(bih0[row] + bhh0[row]);
            }
        }
        float c0_[2][4] = {{0.f,0.f,0.f,0.f},{0.f,0.f,0.f,0.f}};

        // prologue: h0[0] = pointwise(b0 + wx*x[0]) ; h0[-1]=0 so no MFMA
        {
            const float x0 = xrow[0];
            #pragma unroll
            for (int h = 0; h < 2; ++h) {
                s16x4 hw;
                #pragma unroll
                for (int r = 0; r < 4; ++r) {
                    const float pi = fmaf(bfhi(bwx[0 + h][r]), x0, bflo(bwx[0 + h][r]));
                    const float pg = fmaf(bfhi(bwx[4 + h][r]), x0, bflo(bwx[4 + h][r]));
                    const float po = fmaf(bfhi(bwx[6 + h][r]), x0, bflo(bwx[6 + h][r]));
                    const float ig = sigmoidf_(pi);
                    const float gg = tanhf_(pg);
                    const float og = sigmoidf_(po);
                    const float cc = ig * gg;          // f * c(-1) = 0
                    c0_[h][r] = cc;
                    hw[r] = (short)f2bf(og * tanhf_(cc));
                }
                *(s16x4*)&h0f0[h ? fo1 : fo0] = hw;
            }
        }
        __syncthreads();   // staging + prologue visible (pairs with L1's barrier)

        #pragma unroll 1
        for (int k = 0; k < TLEN; k += 2) {
            L0ITER(k,     h0f0, h0f1);
            L0ITER(k + 1, h0f1, h0f0);
        }
    } else {
        // ---- L1 team: Whh1 fully in regs (128, -> acc file) ----
        s16x8 wh1f[4][8];
        #pragma unroll
        for (int c = 0; c < 4; ++c) {
            #pragma unroll
            for (int t2 = 0; t2 < 8; ++t2) {
                const int row = (t2 >> 1) * 128 + 32 * wl + 16 * (t2 & 1) + n;
                const int k0 = c * 32 + q * 8;
                const float* p = Whh1 + row * HDIM + k0;
                s16x8 a;
                #pragma unroll
                for (int j = 0; j < 8; ++j) a[j] = (short)f2bf(p[j]);
                wh1f[c][t2] = a;
            }
        }
        float c1_[2][4] = {{0.f,0.f,0.f,0.f},{0.f,0.f,0.f,0.f}};

        __syncthreads();   // pairs with L0's pre-loop barrier

        #pragma unroll 1
        for (int k = 0; k < TLEN; k += 2) {
            L1ITER(k,     h0f0, h1f1, h1f0);
            L1ITER(k + 1, h0f1, h1f0, h1f1);
        }
        // h1[511] now in h1f1
    }

    __syncthreads();

    // ---- head ----
    if (!isL0) {
        #pragma unroll
        for (int h = 0; h < 2; ++h) {
            const s16x4 hv = *(const s16x4*)&h1f1[h ? fo1 : fo0];
            f32x4 hf;
            #pragma unroll
            for (int r = 0; r < 4; ++r) hf[r] = bf2f(hv[r]);
            *(f32x4*)&headH[n * HDIM + (h ? ub1 : ub0)] = hf;
        }
    }
    __syncthreads();

    #pragma unroll
    for (int rep = 0; rep < 2; ++rep) {
        const int idx = tid + rep * 512;     // 1024 = 16 batch * 64 hidden
        const int nn = idx >> 6, j = idx & 63;
        float s = b1[j];
        const float* wrow = W1 + j * HDIM;
        const float* hrow = headH + nn * HDIM;
        #pragma unroll
        for (int k = 0; k < HDIM; k += 4) {
            const f32x4 hv = *(const f32x4*)&hrow[k];
            const f32x4 wv = *(const f32x4*)&wrow[k];
            s += hv[0]*wv[0] + hv[1]*wv[1] + hv[2]*wv[2] + hv[3]*wv[3];
        }
        headL[nn * 64 + j] = fmaxf(s, 0.0f);
    }
    __syncthreads();

    if (tid < 128) {
        const int nn = tid >> 3, cls = tid & 7;
        float s = b2[cls];
        const float* wrow = W2 + cls * 64;
        const float* hrow = headL + nn * 64;
        #pragma unroll
        for (int k = 0; k < 64; k += 4) {
            const f32x4 hv = *(const f32x4*)&hrow[k];
            const f32x4 wv = *(const f32x4*)&wrow[k];
            s += hv[0]*wv[0] + hv[1]*wv[1] + hv[2]*wv[2] + hv[3]*wv[3];
        }
        out[(size_t)(b0 + nn) * 8 + cls] = s;
    }
#undef L0ITER
#undef L1ITER
}

// ============================================================================
// Fallback (round-6 kernel, 954 us): used when ws_size < 128 KB.
// ============================================================================
__global__ __launch_bounds__(512, 2) void lstm_fused_kernel(
    const float* __restrict__ x,
    const float* __restrict__ Wih0,
    const float* __restrict__ Whh0,
    const float* __restrict__ bih0,
    const float* __restrict__ bhh0,
    const float* __restrict__ Wih1,
    const float* __restrict__ Whh1,
    const float* __restrict__ bih1,
    const float* __restrict__ bhh1,
    const float* __restrict__ W1,
    const float* __restrict__ b1,
    const float* __restrict__ W2,
    const float* __restrict__ b2,
    float* __restrict__ out)
{
    __shared__ __align__(16) short wh1lds[65536];
    __shared__ __align__(16) short h0f0[2048], h0f1[2048];
    __shared__ __align__(16) short h1f0[2048], h1f1[2048];
    __shared__ __align__(16) float b1lds[4][8][16];

    const int tid = threadIdx.x;
    const int w   = tid >> 6;
    const int wl  = w & 3;
    const bool isL0 = (w < 4);
    const int l = tid & 63;
    const int n = l & 15;
    const int q = l >> 4;
    const int b0 = blockIdx.x * BT;
    const float* xrow = x + (size_t)(b0 + n) * TLEN;

    for (int s2 = tid; s2 < 8192; s2 += 512) {
        const int ll = s2 & 63, t2 = (s2 >> 6) & 7, cc = (s2 >> 9) & 3, wv = s2 >> 11;
        const int row = (t2 >> 1) * 128 + 32 * wv + 16 * (t2 & 1) + (ll & 15);
        const int k0  = cc * 32 + (ll >> 4) * 8;
        const float* p = Whh1 + row * HDIM + k0;
        s16x8 a;
        #pragma unroll
        for (int j = 0; j < 8; ++j) a[j] = (short)f2bf(p[j]);
        *(s16x8*)&wh1lds[s2 * 8] = a;
    }
    {
        const int idx = tid;
        const int wv = idx >> 7, t2 = (idx >> 4) & 7, j = idx & 15;
        const int row = (t2 >> 1) * 128 + 32 * wv + 16 * (t2 & 1) + j;
        b1lds[wv][t2][j] = bih1[row] + bhh1[row];
    }
    for (int s2 = tid; s2 < 1024; s2 += 512) ((uint32_t*)h1f1)[s2] = 0u;

    const int ub0 = 32 * wl + 4 * q;
    const int ub1 = ub0 + 16;
    const int fo0 = ((ub0 >> 5) * 64 + n + 16 * ((ub0 >> 3) & 3)) * 8 + (ub0 & 7);
    const int fo1 = ((ub1 >> 5) * 64 + n + 16 * ((ub1 >> 3) & 3)) * 8 + (ub1 & 7);

#define L0ITER(K, R0, W0) do {                                                \
    const int xi_ = (K) + 1;                                                  \
    const float xv_ = xrow[xi_ < TLEN ? xi_ : (TLEN - 1)];                    \
    s16x8 hb_[4];                                                             \
    _Pragma("unroll")                                                         \
    for (int c = 0; c < 4; ++c) hb_[c] = *(const s16x8*)&(R0)[(c * 64 + l) * 8]; \
    f32x4 a_[8];                                                              \
    _Pragma("unroll")                                                         \
    for (int t2 = 0; t2 < 8; ++t2) {                                          \
        _Pragma("unroll")                                                     \
        for (int r = 0; r < 4; ++r)                                           \
            a_[t2][r] = fmaf(bfhi(bwx[t2][r]), xv_, bflo(bwx[t2][r]));        \
    }                                                                         \
    _Pragma("unroll")                                                         \
    for (int c = 0; c < 4; ++c) {                                             \
        _Pragma("unroll")                                                     \
        for (int t2 = 0; t2 < 8; ++t2)                                        \
            a_[t2] = MFMA16(w0f[c][t2], hb_[c], a_[t2]);                      \
    }                                                                         \
    _Pragma("unroll")                                                         \
    for (int h = 0; h < 2; ++h) {                                             \
        s16x4 hw;                                                             \
        _Pragma("unroll")                                                     \
        for (int r = 0; r < 4; ++r) {                                         \
            const float ig = sigmoidf_(a_[0 + h][r]);                         \
            const float fg = sigmoidf_(a_[2 + h][r]);                         \
            const float gg = tanhf_(a_[4 + h][r]);                            \
            const float og = sigmoidf_(a_[6 + h][r]);                         \
            const float cc = fmaf(fg, c0_[h][r], ig * gg);                    \
            c0_[h][r] = cc;                                                   \
            hw[r] = (short)f2bf(og * tanhf_(cc));                             \
        }                                                                     \
        *(s16x4*)&(W0)[h ? fo1 : fo0] = hw;                                   \
    }                                                                         \
    __syncthreads();                                                          \
} while (0)

#define L1ITER(K, R0, R1, W1) do {                                            \
    s16x8 hb0_[4], hb1_[4];                                                   \
    _Pragma("unroll")                                                         \
    for (int c = 0; c < 4; ++c) {                                             \
        hb0_[c] = *(const s16x8*)&(R0)[(c * 64 + l) * 8];                     \
        hb1_[c] = *(const s16x8*)&(R1)[(c * 64 + l) * 8];                     \
    }                                                                         \
    f32x4 a_[8];                                                              \
    _Pragma("unroll")                                                         \
    for (int t2 = 0; t2 < 8; ++t2)                                            \
        a_[t2] = *(const f32x4*)&b1lds[wl][t2][q * 4];                        \
    _Pragma("unroll")                                                         \
    for (int c = 0; c < 4; ++c) {                                             \
        _Pragma("unroll")                                                     \
        for (int t2 = 0; t2 < 8; ++t2)                                        \
            a_[t2] = MFMA16(wi1f[c][t2], hb0_[c], a_[t2]);                    \
    }                                                                         \
    _Pragma("unroll")                                                         \
    for (int c = 0; c < 4; ++c) {                                             \
        s16x8 wt_[8];                                                         \
        _Pragma("unroll")                                                     \
        for (int t2 = 0; t2 < 8; ++t2)                                        \
            wt_[t2] = *(const s16x8*)&wh1lds[(((wl * 4 + c) * 8 + t2) * 64 + l) * 8]; \
        _Pragma("unroll")                                                     \
        for (int t2 = 0; t2 < 8; ++t2)                                        \
            a_[t2] = MFMA16(wt_[t2], hb1_[c], a_[t2]);                        \
    }                                                                         \
    _Pragma("unroll")                                                         \
    for (int h = 0; h < 2; ++h) {                                             \
        s16x4 hw;                                                             \
        _Pragma("unroll")                                                     \
        for (int r = 0; r < 4; ++r) {                                         \
            const float ig = sigmoidf_(a_[0 + h][r]);                         \
            const float fg = sigmoidf_(a_[2 + h][r]);                         \
            const float gg = tanhf_(a_[4 + h][r]);                            \
            const float og = sigmoidf_(a_[6 + h][r]);                         \
            const float cc = fmaf(fg, c1_[h][r], ig * gg);                    \
            c1_[h][r] = cc;                                                   \
            hw[r] = (short)f2bf(og * tanhf_(cc));                             \
        }                                                                     \
        *(s16x4*)&(W1)[h ? fo1 : fo0] = hw;                                   \
    }                                                                         \
    __syncthreads();                                                          \
} while (0)

    if (isL0) {
        s16x8 w0f[4][8];
        #pragma unroll
        for (int c = 0; c < 4; ++c) {
            #pragma unroll
            for (int t2 = 0; t2 < 8; ++t2) {
                const int row = (t2 >> 1) * 128 + 32 * wl + 16 * (t2 & 1) + n;
                const int k0 = c * 32 + q * 8;
                const float* p = Whh0 + row * HDIM + k0;
                s16x8 a;
                #pragma unroll
                for (int j = 0; j < 8; ++j) a[j] = (short)f2bf(p[j]);
                w0f[c][t2] = a;
            }
        }
        u32x4 bwx[8];
        #pragma unroll
        for (int t2 = 0; t2 < 8; ++t2) {
            #pragma unroll
            for (int r = 0; r < 4; ++r) {
                const int row = (t2 >> 1) * 128 + 32 * wl + 16 * (t2 & 1) + 4 * q + r;
                bwx[t2][r] = ((uint32_t)f2bf(Wih0[row]) << 16) | f2bf(bih0[row] + bhh0[row]);
            }
        }
        float c0_[2][4] = {{0.f,0.f,0.f,0.f},{0.f,0.f,0.f,0.f}};
        {
            const float x0 = xrow[0];
            #pragma unroll
            for (int h = 0; h < 2; ++h) {
                s16x4 hw;
                #pragma unroll
                for (int r = 0; r < 4; ++r) {
                    const float pi = fmaf(bfhi(bwx[0 + h][r]), x0, bflo(bwx[0 + h][r]));
                    const float pg = fmaf(bfhi(bwx[4 + h][r]), x0, bflo(bwx[4 + h][r]));
                    const float po = fmaf(bfhi(bwx[6 + h][r]), x0, bflo(bwx[6 + h][r]));
                    const float ig = sigmoidf_(pi);
                    const float gg = tanhf_(pg);
                    const float og = sigmoidf_(po);
                    const float cc = ig * gg;
                    c0_[h][r] = cc;
                    hw[r] = (short)f2bf(og * tanhf_(cc));
                }
                *(s16x4*)&h0f0[h ? fo1 : fo0] = hw;
            }
        }
        __syncthreads();
        #pragma unroll 1
        for (int k = 0; k < TLEN; k += 2) {
            L0ITER(k,     h0f0, h0f1);
            L0ITER(k + 1, h0f1, h0f0);
        }
    } else {
        s16x8 wi1f[4][8];
        #pragma unroll
        for (int c = 0; c < 4; ++c) {
            #pragma unroll
            for (int t2 = 0; t2 < 8; ++t2) {
                const int row = (t2 >> 1) * 128 + 32 * wl + 16 * (t2 & 1) + n;
                const int k0 = c * 32 + q * 8;
                const float* p = Wih1 + row * HDIM + k0;
                s16x8 a;
                #pragma unroll
                for (int j = 0; j < 8; ++j) a[j] = (short)f2bf(p[j]);
                wi1f[c][t2] = a;
            }
        }
        float c1_[2][4] = {{0.f,0.f,0.f,0.f},{0.f,0.f,0.f,0.f}};
        __syncthreads();
        #pragma unroll 1
        for (int k = 0; k < TLEN; k += 2) {
            L1ITER(k,     h0f0, h1f1, h1f0);
            L1ITER(k + 1, h0f1, h1f0, h1f1);
        }
    }

    __syncthreads();

    float* headH = (float*)wh1lds;
    float* headL = headH + 16 * HDIM;
    if (!isL0) {
        #pragma unroll
        for (int h = 0; h < 2; ++h) {
            const s16x4 hv = *(const s16x4*)&h1f1[h ? fo1 : fo0];
            f32x4 hf;
            #pragma unroll
            for (int r = 0; r < 4; ++r) hf[r] = bf2f(hv[r]);
            *(f32x4*)&headH[n * HDIM + (h ? ub1 : ub0)] = hf;
        }
    }
    __syncthreads();

    #pragma unroll
    for (int rep = 0; rep < 2; ++rep) {
        const int idx = tid + rep * 512;
        const int nn = idx >> 6, j = idx & 63;
        float s = b1[j];
        const float* wrow = W1 + j * HDIM;
        const float* hrow = headH + nn * HDIM;
        #pragma unroll
        for (int k = 0; k < HDIM; k += 4) {
            const f32x4 hv = *(const f32x4*)&hrow[k];
            const f32x4 wv = *(const f32x4*)&wrow[k];
            s += hv[0]*wv[0] + hv[1]*wv[1] + hv[2]*wv[2] + hv[3]*wv[3];
        }
        headL[nn * 64 + j] = fmaxf(s, 0.0f);
    }
    __syncthreads();

    if (tid < 128) {
        const int nn = tid >> 3, cls = tid & 7;
        float s = b2[cls];
        const float* wrow = W2 + cls * 64;
        const float* hrow = headL + nn * 64;
        #pragma unroll
        for (int k = 0; k < 64; k += 4) {
            const f32x4 hv = *(const f32x4*)&hrow[k];
            const f32x4 wv = *(const f32x4*)&wrow[k];
            s += hv[0]*wv[0] + hv[1]*wv[1] + hv[2]*wv[2] + hv[3]*wv[3];
        }
        out[(size_t)(b0 + nn) * 8 + cls] = s;
    }
#undef L0ITER
#undef L1ITER
}

extern "C" void kernel_launch(void* const* d_in, const int* in_sizes, int n_in,
                              void* d_out, int out_size, void* d_ws, size_t ws_size,
                              hipStream_t stream) {
    const float* x    = (const float*)d_in[0];
    const float* Wih0 = (const float*)d_in[1];
    const float* Whh0 = (const float*)d_in[2];
    const float* bih0 = (const float*)d_in[3];
    const float* bhh0 = (const float*)d_in[4];
    const float* Wih1 = (const float*)d_in[5];
    const float* Whh1 = (const float*)d_in[6];
    const float* bih1 = (const float*)d_in[7];
    const float* bhh1 = (const float*)d_in[8];
    const float* W1   = (const float*)d_in[9];
    const float* b1   = (const float*)d_in[10];
    const float* W2   = (const float*)d_in[11];
    const float* b2   = (const float*)d_in[12];
    float* outp = (float*)d_out;

    const size_t PACK_BYTES = (size_t)512 * 128 * sizeof(short);   // 128 KB

    if (ws_size >= PACK_BYTES) {
        short* wih1pk = (short*)d_ws;
        pack_wih1_kernel<<<8, 1024, 0, stream>>>(Wih1, wih1pk);
        lstm_allreg_kernel<<<128, 512, 0, stream>>>(
            x, Wih0, Whh0, bih0, bhh0, Whh1, bih1, bhh1,
            W1, b1, W2, b2, wih1pk, outp);
    } else {
        lstm_fused_kernel<<<128, 512, 0, stream>>>(
            x, Wih0, Whh0, bih0, bhh0, Wih1, Whh1, bih1, bhh1,
            W1, b1, W2, b2, outp);
    }
}

// Round 15
// 1257.347 us; speedup vs baseline: 1.5185x; 1.1407x over previous
//
#include <hip/hip_runtime.h>
#include <stdint.h>

typedef float f32x4 __attribute__((ext_vector_type(4)));
typedef short s16x8 __attribute__((ext_vector_type(8)));
typedef short s16x4 __attribute__((ext_vector_type(4)));
typedef uint32_t u32x4 __attribute__((ext_vector_type(4)));

#define HDIM 128
#define TLEN 512
#define BT 16

__device__ __forceinline__ unsigned short f2bf(float f) {
    union { float f; uint32_t u; } v; v.f = f;
    uint32_t r = v.u + 0x7FFFu + ((v.u >> 16) & 1u);
    return (unsigned short)(r >> 16);
}
__device__ __forceinline__ float bfhi(uint32_t u){ union{uint32_t u;float f;}v; v.u = u & 0xFFFF0000u; return v.f; }
__device__ __forceinline__ float bflo(uint32_t u){ union{uint32_t u;float f;}v; v.u = u << 16; return v.f; }
__device__ __forceinline__ float bf2f(short s){ union{uint32_t u;float f;}v; v.u = ((uint32_t)(unsigned short)s) << 16; return v.f; }

__device__ __forceinline__ float sigmoidf_(float x){
    float e = __expf(-x);
    return __builtin_amdgcn_rcpf(1.0f + e);
}
__device__ __forceinline__ float tanhf_(float x){
    float e = __expf(2.0f * x);
    return 1.0f - 2.0f * __builtin_amdgcn_rcpf(1.0f + e);
}

#define MFMA16(A, B, C) __builtin_amdgcn_mfma_f32_16x16x32_bf16((A), (B), (C), 0, 0, 0)

// ============================================================================
// Pack kernel: Wih1 (f32, 512x128) -> bf16 fragment-ordered in d_ws.
// Fragment F(wl,c,t) = (wl*4+c)*4+t ; lane l ; shorts at (F*64+l)*8.
// ============================================================================
__global__ __launch_bounds__(1024) void pack_wih1_kernel(
    const float* __restrict__ Wih1, short* __restrict__ dst)
{
    const int s2 = blockIdx.x * 1024 + threadIdx.x;   // 0..8191
    const int ll = s2 & 63;
    const int t  = (s2 >> 6) & 3;
    const int c  = (s2 >> 8) & 3;
    const int wl = s2 >> 10;
    const float* p = Wih1 + (t * 128 + wl * 16 + (ll & 15)) * HDIM + c * 32 + (ll >> 4) * 8;
    s16x8 a;
    #pragma unroll
    for (int j = 0; j < 8; ++j) a[j] = (short)f2bf(p[j]);
    *(s16x8*)&dst[s2 * 8] = a;
}

// ============================================================================
// Main (round-11 base + deltas): 128 blocks x 1024 threads (16 waves, 4/SIMD).
// L0 (w<8): Whh0 in regs (64/wave) + b0wx LDS table (unchanged, proven).
// L1 (w>=8): Whh1 c=0,1 in regs (32/wave), c=2,3 from 64KB LDS; Wih1 from L2
// (packed ws); bias1 in regs (16). setprio around MFMA clusters.
// ============================================================================
__global__ __launch_bounds__(1024, 4) void lstm_mega_kernel(
    const float* __restrict__ x,
    const float* __restrict__ Wih0,
    const float* __restrict__ Whh0,
    const float* __restrict__ bih0,
    const float* __restrict__ bhh0,
    const float* __restrict__ Whh1,
    const float* __restrict__ bih1,
    const float* __restrict__ bhh1,
    const float* __restrict__ W1,
    const float* __restrict__ b1,
    const float* __restrict__ W2,
    const float* __restrict__ b2,
    const short* __restrict__ wih1pk,   // packed bf16 fragments in ws
    float* __restrict__ out)
{
    __shared__ __align__(16) short whh1lds[32768];      // 64 KB: Whh1 c=2,3 only
    __shared__ __align__(16) short h0f[2][2048];        // 8 KB
    __shared__ __align__(16) short h1f[2][2048];        // 8 KB
    __shared__ __align__(16) uint32_t b0wx[8][4][16];   // (wx<<16)|bias0, 2 KB

    const int tid = threadIdx.x;
    const int w   = tid >> 6;        // 0..15
    const int wl  = w & 7;           // wave-in-team; owns units [16wl,16wl+16)
    const bool isL0 = (w < 8);
    const int l = tid & 63;
    const int n = l & 15;            // batch col
    const int q = l >> 4;            // k-group / row-quad
    const int b0 = blockIdx.x * BT;
    const float* xrow = x + (size_t)(b0 + n) * TLEN;

    // ---- stage Whh1 c=2,3 into LDS fragment-ordered (4 frags per thread) ----
    #pragma unroll
    for (int i = 0; i < 4; ++i) {
        const int s2 = tid + i * 1024;                  // 0..4095
        const int ll = s2 & 63, t = (s2 >> 6) & 3, c2 = (s2 >> 8) & 1, wv = (s2 >> 9) & 7;
        const float* p = Whh1 + (t * 128 + wv * 16 + (ll & 15)) * HDIM + (c2 + 2) * 32 + (ll >> 4) * 8;
        s16x8 a;
        #pragma unroll
        for (int j = 0; j < 8; ++j) a[j] = (short)f2bf(p[j]);
        *(s16x8*)&whh1lds[s2 * 8] = a;
    }
    // ---- b0wx table (512 entries) ----
    if (tid < 512) {
        const int wv = tid >> 6, t = (tid >> 4) & 3, j = tid & 15;
        const int row = t * 128 + wv * 16 + j;
        b0wx[wv][t][j] = ((uint32_t)f2bf(Wih0[row]) << 16) | f2bf(bih0[row] + bhh0[row]);
    }
    // zero h1[-1] (read at k=0 from h1f[1]): 1024 u32, one per thread
    ((uint32_t*)h1f[1])[tid] = 0u;

    // B-fragment write slot for this lane's 4 units
    const int u0 = wl * 16 + q * 4;
    const int fragoff = ((u0 >> 5) * 64 + n + 16 * ((u0 >> 3) & 3)) * 8 + (u0 & 7);

#define L0ITER(K, R, W) do {                                                  \
    const int xi_ = (K) + 1;                                                  \
    const float xv_ = xrow[xi_ < TLEN ? xi_ : (TLEN - 1)];                    \
    s16x8 hb_[4];                                                             \
    _Pragma("unroll")                                                         \
    for (int c = 0; c < 4; ++c) hb_[c] = *(const s16x8*)&(R)[(c * 64 + l) * 8]; \
    f32x4 acc_[4];                                                            \
    _Pragma("unroll")                                                         \
    for (int t = 0; t < 4; ++t) {                                             \
        const u32x4 bwt = *(const u32x4*)&b0wx[wl][t][q * 4];                 \
        _Pragma("unroll")                                                     \
        for (int r = 0; r < 4; ++r)                                           \
            acc_[t][r] = fmaf(bfhi(bwt[r]), xv_, bflo(bwt[r]));               \
    }                                                                         \
    __builtin_amdgcn_s_setprio(1);                                            \
    _Pragma("unroll")                                                         \
    for (int c = 0; c < 4; ++c) {                                             \
        _Pragma("unroll")                                                     \
        for (int t = 0; t < 4; ++t)                                           \
            acc_[t] = MFMA16(w0f[c][t], hb_[c], acc_[t]);                     \
    }                                                                         \
    __builtin_amdgcn_s_setprio(0);                                            \
    s16x4 hw_;                                                                \
    _Pragma("unroll")                                                         \
    for (int r = 0; r < 4; ++r) {                                             \
        const float ig = sigmoidf_(acc_[0][r]);                               \
        const float fg = sigmoidf_(acc_[1][r]);                               \
        const float gg = tanhf_(acc_[2][r]);                                  \
        const float og = sigmoidf_(acc_[3][r]);                               \
        const float cc = fmaf(fg, c0v[r], ig * gg);                           \
        c0v[r] = cc;                                                          \
        hw_[r] = (short)f2bf(og * tanhf_(cc));                                \
    }                                                                         \
    *(s16x4*)&(W)[fragoff] = hw_;                                             \
    __syncthreads();                                                          \
} while (0)

// L1: Whh1 c=0,1 from regs, c=2,3 from LDS; Wih1 from packed global;
// bias from regs; hb loaded per-c (short live ranges).
#define L1ITER(K, R0, R1, W1B) do {                                           \
    f32x4 acc_[4];                                                            \
    _Pragma("unroll")                                                         \
    for (int t = 0; t < 4; ++t) acc_[t] = b1r[t];                             \
    __builtin_amdgcn_s_setprio(1);                                            \
    _Pragma("unroll")                                                         \
    for (int c = 0; c < 2; ++c) {                                             \
        const s16x8 hb0_ = *(const s16x8*)&(R0)[(c * 64 + l) * 8];            \
        const s16x8 hb1_ = *(const s16x8*)&(R1)[(c * 64 + l) * 8];            \
        s16x8 wi_[4];                                                         \
        _Pragma("unroll")                                                     \
        for (int t4 = 0; t4 < 4; ++t4)                                        \
            wi_[t4] = *(const s16x8*)&wih1pk[(((wl * 4 + c) * 4 + t4) * 64 + l) * 8]; \
        _Pragma("unroll")                                                     \
        for (int t = 0; t < 4; ++t)                                           \
            acc_[t] = MFMA16(wh1r[c][t], hb1_, acc_[t]);                      \
        _Pragma("unroll")                                                     \
        for (int t = 0; t < 4; ++t)                                           \
            acc_[t] = MFMA16(wi_[t], hb0_, acc_[t]);                          \
    }                                                                         \
    _Pragma("unroll")                                                         \
    for (int c = 2; c < 4; ++c) {                                             \
        const s16x8 hb0_ = *(const s16x8*)&(R0)[(c * 64 + l) * 8];            \
        const s16x8 hb1_ = *(const s16x8*)&(R1)[(c * 64 + l) * 8];            \
        s16x8 wt_[4], wi_[4];                                                 \
        _Pragma("unroll")                                                     \
        for (int t = 0; t < 4; ++t)                                           \
            wt_[t] = *(const s16x8*)&whh1lds[(((wl * 2 + (c - 2)) * 4 + t) * 64 + l) * 8]; \
        _Pragma("unroll")                                                     \
        for (int t4 = 0; t4 < 4; ++t4)                                        \
            wi_[t4] = *(const s16x8*)&wih1pk[(((wl * 4 + c) * 4 + t4) * 64 + l) * 8]; \
        _Pragma("unroll")                                                     \
        for (int t = 0; t < 4; ++t)                                           \
            acc_[t] = MFMA16(wt_[t], hb1_, acc_[t]);                          \
        _Pragma("unroll")                                                     \
        for (int t = 0; t < 4; ++t)                                           \
            acc_[t] = MFMA16(wi_[t], hb0_, acc_[t]);                          \
    }                                                                         \
    __builtin_amdgcn_s_setprio(0);                                            \
    s16x4 hw_;                                                                \
    _Pragma("unroll")                                                         \
    for (int r = 0; r < 4; ++r) {                                             \
        const float ig = sigmoidf_(acc_[0][r]);                               \
        const float fg = sigmoidf_(acc_[1][r]);                               \
        const float gg = tanhf_(acc_[2][r]);                                  \
        const float og = sigmoidf_(acc_[3][r]);                               \
        const float cc = fmaf(fg, c1v[r], ig * gg);                           \
        c1v[r] = cc;                                                          \
        hw_[r] = (short)f2bf(og * tanhf_(cc));                                \
    }                                                                         \
    *(s16x4*)&(W1B)[fragoff] = hw_;                                           \
    __syncthreads();                                                          \
} while (0)

    if (isL0) {
        // ---- L0 wave: Whh0 fragments for its 16 units (64 regs) ----
        s16x8 w0f[4][4];   // [c][t]
        #pragma unroll
        for (int c = 0; c < 4; ++c) {
            #pragma unroll
            for (int t = 0; t < 4; ++t) {
                const float* p = Whh0 + (t * 128 + wl * 16 + n) * HDIM + c * 32 + q * 8;
                s16x8 a;
                #pragma unroll
                for (int j = 0; j < 8; ++j) a[j] = (short)f2bf(p[j]);
                w0f[c][t] = a;
            }
        }
        float c0v[4] = {0.f, 0.f, 0.f, 0.f};

        __syncthreads();   // staging (whh1lds, b0wx, h1f[1]) visible

        // prologue: h0[0] = pointwise(b0 + wx*x[0]) ; h0[-1]=0 so no MFMA
        {
            const float x0 = xrow[0];
            const u32x4 bw0 = *(const u32x4*)&b0wx[wl][0][q * 4];
            const u32x4 bw2 = *(const u32x4*)&b0wx[wl][2][q * 4];
            const u32x4 bw3 = *(const u32x4*)&b0wx[wl][3][q * 4];
            s16x4 hw;
            #pragma unroll
            for (int r = 0; r < 4; ++r) {
                const float pi = fmaf(bfhi(bw0[r]), x0, bflo(bw0[r]));
                const float pg = fmaf(bfhi(bw2[r]), x0, bflo(bw2[r]));
                const float po = fmaf(bfhi(bw3[r]), x0, bflo(bw3[r]));
                const float ig = sigmoidf_(pi);
                const float gg = tanhf_(pg);
                const float og = sigmoidf_(po);
                const float cc = ig * gg;          // f * c(-1) = 0
                c0v[r] = cc;
                hw[r] = (short)f2bf(og * tanhf_(cc));
            }
            *(s16x4*)&h0f[0][fragoff] = hw;
        }
        __syncthreads();   // h0[0] visible

        #pragma unroll 1
        for (int k = 0; k < TLEN; k += 2) {
            L0ITER(k,     h0f[0], h0f[1]);
            L0ITER(k + 1, h0f[1], h0f[0]);
        }
    } else {
        // ---- L1 wave: Whh1 c=0,1 fragments (32 regs) + bias1 (16 regs) ----
        s16x8 wh1r[2][4];
        #pragma unroll
        for (int c = 0; c < 2; ++c) {
            #pragma unroll
            for (int t = 0; t < 4; ++t) {
                const float* p = Whh1 + (t * 128 + wl * 16 + n) * HDIM + c * 32 + q * 8;
                s16x8 a;
                #pragma unroll
                for (int j = 0; j < 8; ++j) a[j] = (short)f2bf(p[j]);
                wh1r[c][t] = a;
            }
        }
        f32x4 b1r[4];
        #pragma unroll
        for (int t = 0; t < 4; ++t) {
            #pragma unroll
            for (int r = 0; r < 4; ++r) {
                const int row = t * 128 + wl * 16 + q * 4 + r;
                b1r[t][r] = bih1[row] + bhh1[row];
            }
        }
        float c1v[4] = {0.f, 0.f, 0.f, 0.f};

        __syncthreads();   // pairs with L0 post-staging barrier
        __syncthreads();   // pairs with L0 post-prologue barrier

        #pragma unroll 1
        for (int k = 0; k < TLEN; k += 2) {
            L1ITER(k,     h0f[0], h1f[1], h1f[0]);
            L1ITER(k + 1, h0f[1], h1f[0], h1f[1]);
        }
        // h1[511] now in h1f[1]
    }

    // ---- head: scratch aliases whh1lds (weights dead after last barrier) ----
    float* headH = (float*)whh1lds;          // [16][128] f32 = 8 KB
    float* headL = headH + 16 * HDIM;        // [16][64]  = 4 KB
    __syncthreads();                         // all loop barriers retired; weights dead
    if (!isL0) {
        const s16x4 hv = *(const s16x4*)&h1f[1][fragoff];
        f32x4 hf;
        #pragma unroll
        for (int r = 0; r < 4; ++r) hf[r] = bf2f(hv[r]);
        *(f32x4*)&headH[n * HDIM + u0] = hf;
    }
    __syncthreads();

    {   // hidden = relu(h @ W1^T + b1): 1024 threads = 16 batch x 64 hidden
        const int nn = tid >> 6, j = tid & 63;
        float s = b1[j];
        const float* wrow = W1 + j * HDIM;
        const float* hrow = headH + nn * HDIM;
        #pragma unroll
        for (int k = 0; k < HDIM; k += 4) {
            const f32x4 hv = *(const f32x4*)&hrow[k];
            const f32x4 wv = *(const f32x4*)&wrow[k];
            s += hv[0]*wv[0] + hv[1]*wv[1] + hv[2]*wv[2] + hv[3]*wv[3];
        }
        headL[nn * 64 + j] = fmaxf(s, 0.0f);
    }
    __syncthreads();

    if (tid < 128) {
        const int nn = tid >> 3, cls = tid & 7;
        float s = b2[cls];
        const float* wrow = W2 + cls * 64;
        const float* hrow = headL + nn * 64;
        #pragma unroll
        for (int k = 0; k < 64; k += 4) {
            const f32x4 hv = *(const f32x4*)&hrow[k];
            const f32x4 wv = *(const f32x4*)&wrow[k];
            s += hv[0]*wv[0] + hv[1]*wv[1] + hv[2]*wv[2] + hv[3]*wv[3];
        }
        out[(size_t)(b0 + nn) * 8 + cls] = s;
    }
#undef L0ITER
#undef L1ITER
}

// ============================================================================
// Fallback (round-6 kernel, 954 us): used when ws_size < 128 KB.
// ============================================================================
__global__ __launch_bounds__(512, 2) void lstm_fused_kernel(
    const float* __restrict__ x,
    const float* __restrict__ Wih0,
    const float* __restrict__ Whh0,
    const float* __restrict__ bih0,
    const float* __restrict__ bhh0,
    const float* __restrict__ Wih1,
    const float* __restrict__ Whh1,
    const float* __restrict__ bih1,
    const float* __restrict__ bhh1,
    const float* __restrict__ W1,
    const float* __restrict__ b1,
    const float* __restrict__ W2,
    const float* __restrict__ b2,
    float* __restrict__ out)
{
    __shared__ __align__(16) short wh1lds[65536];
    __shared__ __align__(16) short h0f0[2048], h0f1[2048];
    __shared__ __align__(16) short h1f0[2048], h1f1[2048];
    __shared__ __align__(16) float b1lds[4][8][16];

    const int tid = threadIdx.x;
    const int w   = tid >> 6;
    const int wl  = w & 3;
    const bool isL0 = (w < 4);
    const int l = tid & 63;
    const int n = l & 15;
    const int q = l >> 4;
    const int b0 = blockIdx.x * BT;
    const float* xrow = x + (size_t)(b0 + n) * TLEN;

    for (int s2 = tid; s2 < 8192; s2 += 512) {
        const int ll = s2 & 63, t2 = (s2 >> 6) & 7, cc = (s2 >> 9) & 3, wv = s2 >> 11;
        const int row = (t2 >> 1) * 128 + 32 * wv + 16 * (t2 & 1) + (ll & 15);
        const int k0  = cc * 32 + (ll >> 4) * 8;
        const float* p = Whh1 + row * HDIM + k0;
        s16x8 a;
        #pragma unroll
        for (int j = 0; j < 8; ++j) a[j] = (short)f2bf(p[j]);
        *(s16x8*)&wh1lds[s2 * 8] = a;
    }
    {
        const int idx = tid;
        const int wv = idx >> 7, t2 = (idx >> 4) & 7, j = idx & 15;
        const int row = (t2 >> 1) * 128 + 32 * wv + 16 * (t2 & 1) + j;
        b1lds[wv][t2][j] = bih1[row] + bhh1[row];
    }
    for (int s2 = tid; s2 < 1024; s2 += 512) ((uint32_t*)h1f1)[s2] = 0u;

    const int ub0 = 32 * wl + 4 * q;
    const int ub1 = ub0 + 16;
    const int fo0 = ((ub0 >> 5) * 64 + n + 16 * ((ub0 >> 3) & 3)) * 8 + (ub0 & 7);
    const int fo1 = ((ub1 >> 5) * 64 + n + 16 * ((ub1 >> 3) & 3)) * 8 + (ub1 & 7);

#define L0ITER(K, R0, W0) do {                                                \
    const int xi_ = (K) + 1;                                                  \
    const float xv_ = xrow[xi_ < TLEN ? xi_ : (TLEN - 1)];                    \
    s16x8 hb_[4];                                                             \
    _Pragma("unroll")                                                         \
    for (int c = 0; c < 4; ++c) hb_[c] = *(const s16x8*)&(R0)[(c * 64 + l) * 8]; \
    f32x4 a_[8];                                                              \
    _Pragma("unroll")                                                         \
    for (int t2 = 0; t2 < 8; ++t2) {                                          \
        _Pragma("unroll")                                                     \
        for (int r = 0; r < 4; ++r)                                           \
            a_[t2][r] = fmaf(bfhi(bwx[t2][r]), xv_, bflo(bwx[t2][r]));        \
    }                                                                         \
    _Pragma("unroll")                                                         \
    for (int c = 0; c < 4; ++c) {                                             \
        _Pragma("unroll")                                                     \
        for (int t2 = 0; t2 < 8; ++t2)                                        \
            a_[t2] = MFMA16(w0f[c][t2], hb_[c], a_[t2]);                      \
    }                                                                         \
    _Pragma("unroll")                                                         \
    for (int h = 0; h < 2; ++h) {                                             \
        s16x4 hw;                                                             \
        _Pragma("unroll")                                                     \
        for (int r = 0; r < 4; ++r) {                                         \
            const float ig = sigmoidf_(a_[0 + h][r]);                         \
            const float fg = sigmoidf_(a_[2 + h][r]);                         \
            const float gg = tanhf_(a_[4 + h][r]);                            \
            const float og = sigmoidf_(a_[6 + h][r]);                         \
            const float cc = fmaf(fg, c0_[h][r], ig * gg);                    \
            c0_[h][r] = cc;                                                   \
            hw[r] = (short)f2bf(og * tanhf_(cc));                             \
        }                                                                     \
        *(s16x4*)&(W0)[h ? fo1 : fo0] = hw;                                   \
    }                                                                         \
    __syncthreads();                                                          \
} while (0)

#define L1ITER(K, R0, R1, W1) do {                                            \
    s16x8 hb0_[4], hb1_[4];                                                   \
    _Pragma("unroll")                                                         \
    for (int c = 0; c < 4; ++c) {                                             \
        hb0_[c] = *(const s16x8*)&(R0)[(c * 64 + l) * 8];                     \
        hb1_[c] = *(const s16x8*)&(R1)[(c * 64 + l) * 8];                     \
    }                                                                         \
    f32x4 a_[8];                                                              \
    _Pragma("unroll")                                                         \
    for (int t2 = 0; t2 < 8; ++t2)                                            \
        a_[t2] = *(const f32x4*)&b1lds[wl][t2][q * 4];                        \
    _Pragma("unroll")                                                         \
    for (int c = 0; c < 4; ++c) {                                             \
        _Pragma("unroll")                                                     \
        for (int t2 = 0; t2 < 8; ++t2)                                        \
            a_[t2] = MFMA16(wi1f[c][t2], hb0_[c], a_[t2]);                    \
    }                                                                         \
    _Pragma("unroll")                                                         \
    for (int c = 0; c < 4; ++c) {                                             \
        s16x8 wt_[8];                                                         \
        _Pragma("unroll")                                                     \
        for (int t2 = 0; t2 < 8; ++t2)                                        \
            wt_[t2] = *(const s16x8*)&wh1lds[(((wl * 4 + c) * 8 + t2) * 64 + l) * 8]; \
        _Pragma("unroll")                                                     \
        for (int t2 = 0; t2 < 8; ++t2)                                        \
            a_[t2] = MFMA16(wt_[t2], hb1_[c], a_[t2]);                        \
    }                                                                         \
    _Pragma("unroll")                                                         \
    for (int h = 0; h < 2; ++h) {                                             \
        s16x4 hw;                                                             \
        _Pragma("unroll")                                                     \
        for (int r = 0; r < 4; ++r) {                                         \
            const float ig = sigmoidf_(a_[0 + h][r]);                         \
            const float fg = sigmoidf_(a_[2 + h][r]);                         \
            const float gg = tanhf_(a_[4 + h][r]);                            \
            const float og = sigmoidf_(a_[6 + h][r]);                         \
            const float cc = fmaf(fg, c1_[h][r], ig * gg);                    \
            c1_[h][r] = cc;                                                   \
            hw[r] = (short)f2bf(og * tanhf_(cc));                             \
        }                                                                     \
        *(s16x4*)&(W1)[h ? fo1 : fo0] = hw;                                   \
    }                                                                         \
    __syncthreads();                                                          \
} while (0)

    if (isL0) {
        s16x8 w0f[4][8];
        #pragma unroll
        for (int c = 0; c < 4; ++c) {
            #pragma unroll
            for (int t2 = 0; t2 < 8; ++t2) {
                const int row = (t2 >> 1) * 128 + 32 * wl + 16 * (t2 & 1) + n;
                const int k0 = c * 32 + q * 8;
                const float* p = Whh0 + row * HDIM + k0;
                s16x8 a;
                #pragma unroll
                for (int j = 0; j < 8; ++j) a[j] = (short)f2bf(p[j]);
                w0f[c][t2] = a;
            }
        }
        u32x4 bwx[8];
        #pragma unroll
        for (int t2 = 0; t2 < 8; ++t2) {
            #pragma unroll
            for (int r = 0; r < 4; ++r) {
                const int row = (t2 >> 1) * 128 + 32 * wl + 16 * (t2 & 1) + 4 * q + r;
                bwx[t2][r] = ((uint32_t)f2bf(Wih0[row]) << 16) | f2bf(bih0[row] + bhh0[row]);
            }
        }
        float c0_[2][4] = {{0.f,0.f,0.f,0.f},{0.f,0.f,0.f,0.f}};
        {
            const float x0 = xrow[0];
            #pragma unroll
            for (int h = 0; h < 2; ++h) {
                s16x4 hw;
                #pragma unroll
                for (int r = 0; r < 4; ++r) {
                    const float pi = fmaf(bfhi(bwx[0 + h][r]), x0, bflo(bwx[0 + h][r]));
                    const float pg = fmaf(bfhi(bwx[4 + h][r]), x0, bflo(bwx[4 + h][r]));
                    const float po = fmaf(bfhi(bwx[6 + h][r]), x0, bflo(bwx[6 + h][r]));
                    const float ig = sigmoidf_(pi);
                    const float gg = tanhf_(pg);
                    const float og = sigmoidf_(po);
                    const float cc = ig * gg;
                    c0_[h][r] = cc;
                    hw[r] = (short)f2bf(og * tanhf_(cc));
                }
                *(s16x4*)&h0f0[h ? fo1 : fo0] = hw;
            }
        }
        __syncthreads();
        #pragma unroll 1
        for (int k = 0; k < TLEN; k += 2) {
            L0ITER(k,     h0f0, h0f1);
            L0ITER(k + 1, h0f1, h0f0);
        }
    } else {
        s16x8 wi1f[4][8];
        #pragma unroll
        for (int c = 0; c < 4; ++c) {
            #pragma unroll
            for (int t2 = 0; t2 < 8; ++t2) {
                const int row = (t2 >> 1) * 128 + 32 * wl + 16 * (t2 & 1) + n;
                const int k0 = c * 32 + q * 8;
                const float* p = Wih1 + row * HDIM + k0;
                s16x8 a;
                #pragma unroll
                for (int j = 0; j < 8; ++j) a[j] = (short)f2bf(p[j]);
                wi1f[c][t2] = a;
            }
        }
        float c1_[2][4] = {{0.f,0.f,0.f,0.f},{0.f,0.f,0.f,0.f}};
        __syncthreads();
        #pragma unroll 1
        for (int k = 0; k < TLEN; k += 2) {
            L1ITER(k,     h0f0, h1f1, h1f0);
            L1ITER(k + 1, h0f1, h1f0, h1f1);
        }
    }

    __syncthreads();

    float* headH = (float*)wh1lds;
    float* headL = headH + 16 * HDIM;
    if (!isL0) {
        #pragma unroll
        for (int h = 0; h < 2; ++h) {
            const s16x4 hv = *(const s16x4*)&h1f1[h ? fo1 : fo0];
            f32x4 hf;
            #pragma unroll
            for (int r = 0; r < 4; ++r) hf[r] = bf2f(hv[r]);
            *(f32x4*)&headH[n * HDIM + (h ? ub1 : ub0)] = hf;
        }
    }
    __syncthreads();

    #pragma unroll
    for (int rep = 0; rep < 2; ++rep) {
        const int idx = tid + rep * 512;
        const int nn = idx >> 6, j = idx & 63;
        float s = b1[j];
        const float* wrow = W1 + j * HDIM;
        const float* hrow = headH + nn * HDIM;
        #pragma unroll
        for (int k = 0; k < HDIM; k += 4) {
            const f32x4 hv = *(const f32x4*)&hrow[k];
            const f32x4 wv = *(const f32x4*)&wrow[k];
            s += hv[0]*wv[0] + hv[1]*wv[1] + hv[2]*wv[2] + hv[3]*wv[3];
        }
        headL[nn * 64 + j] = fmaxf(s, 0.0f);
    }
    __syncthreads();

    if (tid < 128) {
        const int nn = tid >> 3, cls = tid & 7;
        float s = b2[cls];
        const float* wrow = W2 + cls * 64;
        const float* hrow = headL + nn * 64;
        #pragma unroll
        for (int k = 0; k < 64; k += 4) {
            const f32x4 hv = *(const f32x4*)&hrow[k];
            const f32x4 wv = *(const f32x4*)&wrow[k];
            s += hv[0]*wv[0] + hv[1]*wv[1] + hv[2]*wv[2] + hv[3]*wv[3];
        }
        out[(size_t)(b0 + nn) * 8 + cls] = s;
    }
#undef L0ITER
#undef L1ITER
}

extern "C" void kernel_launch(void* const* d_in, const int* in_sizes, int n_in,
                              void* d_out, int out_size, void* d_ws, size_t ws_size,
                              hipStream_t stream) {
    const float* x    = (const float*)d_in[0];
    const float* Wih0 = (const float*)d_in[1];
    const float* Whh0 = (const float*)d_in[2];
    const float* bih0 = (const float*)d_in[3];
    const float* bhh0 = (const float*)d_in[4];
    const float* Wih1 = (const float*)d_in[5];
    const float* Whh1 = (const float*)d_in[6];
    const float* bih1 = (const float*)d_in[7];
    const float* bhh1 = (const float*)d_in[8];
    const float* W1   = (const float*)d_in[9];
    const float* b1   = (const float*)d_in[10];
    const float* W2   = (const float*)d_in[11];
    const float* b2   = (const float*)d_in[12];
    float* outp = (float*)d_out;

    const size_t PACK_BYTES = (size_t)512 * 128 * sizeof(short);   // 128 KB

    if (ws_size >= PACK_BYTES) {
        short* wih1pk = (short*)d_ws;
        pack_wih1_kernel<<<8, 1024, 0, stream>>>(Wih1, wih1pk);
        lstm_mega_kernel<<<128, 1024, 0, stream>>>(
            x, Wih0, Whh0, bih0, bhh0, Whh1, bih1, bhh1,
            W1, b1, W2, b2, wih1pk, outp);
    } else {
        lstm_fused_kernel<<<128, 512, 0, stream>>>(
            x, Wih0, Whh0, bih0, bhh0, Wih1, Whh1, bih1, bhh1,
            W1, b1, W2, b2, outp);
    }
}

// Round 16
// 993.820 us; speedup vs baseline: 1.9211x; 1.2652x over previous
//
#include <hip/hip_runtime.h>
#include <stdint.h>

typedef float f32x4 __attribute__((ext_vector_type(4)));
typedef short s16x8 __attribute__((ext_vector_type(8)));
typedef short s16x4 __attribute__((ext_vector_type(4)));
typedef uint32_t u32x4 __attribute__((ext_vector_type(4)));

#define HDIM 128
#define TLEN 512
#define BT 16

__device__ __forceinline__ unsigned short f2bf(float f) {
    union { float f; uint32_t u; } v; v.f = f;
    uint32_t r = v.u + 0x7FFFu + ((v.u >> 16) & 1u);
    return (unsigned short)(r >> 16);
}
__device__ __forceinline__ float bfhi(uint32_t u){ union{uint32_t u;float f;}v; v.u = u & 0xFFFF0000u; return v.f; }
__device__ __forceinline__ float bflo(uint32_t u){ union{uint32_t u;float f;}v; v.u = u << 16; return v.f; }
__device__ __forceinline__ float bf2f(short s){ union{uint32_t u;float f;}v; v.u = ((uint32_t)(unsigned short)s) << 16; return v.f; }

__device__ __forceinline__ float sigmoidf_(float x){
    float e = __expf(-x);
    return __builtin_amdgcn_rcpf(1.0f + e);
}
__device__ __forceinline__ float tanhf_(float x){
    float e = __expf(2.0f * x);
    return 1.0f - 2.0f * __builtin_amdgcn_rcpf(1.0f + e);
}

#define MFMA16(A, B, C) __builtin_amdgcn_mfma_f32_16x16x32_bf16((A), (B), (C), 0, 0, 0)

// ============================================================================
// Pack kernel: Wih1 (f32, 512x128) -> bf16 fragment-ordered in d_ws.
// Fragment F(wl,c,t) = (wl*4+c)*4+t ; lane l ; shorts at (F*64+l)*8.
// ============================================================================
__global__ __launch_bounds__(1024) void pack_wih1_kernel(
    const float* __restrict__ Wih1, short* __restrict__ dst)
{
    const int s2 = blockIdx.x * 1024 + threadIdx.x;   // 0..8191
    const int ll = s2 & 63;
    const int t  = (s2 >> 6) & 3;
    const int c  = (s2 >> 8) & 3;
    const int wl = s2 >> 10;
    const float* p = Wih1 + (t * 128 + wl * 16 + (ll & 15)) * HDIM + c * 32 + (ll >> 4) * 8;
    s16x8 a;
    #pragma unroll
    for (int j = 0; j < 8; ++j) a[j] = (short)f2bf(p[j]);
    *(s16x8*)&dst[s2 * 8] = a;
}

// ============================================================================
// Main (round-11 structure, proven 891 us, + s_setprio around MFMA clusters):
// 128 blocks x 1024 threads (16 waves, 4/SIMD). Teams of 8 waves:
// L0 (w<8): Whh0 in regs/AGPRs (64), 16 units/wave. L1 (w>=8): Whh1 from LDS,
// Wih1 from global L2 (packed bf16 in ws), ZERO persistent L1 weight regs.
// 1 barrier/step.
// ============================================================================
__global__ __launch_bounds__(1024, 4) void lstm_mega_kernel(
    const float* __restrict__ x,
    const float* __restrict__ Wih0,
    const float* __restrict__ Whh0,
    const float* __restrict__ bih0,
    const float* __restrict__ bhh0,
    const float* __restrict__ Whh1,
    const float* __restrict__ bih1,
    const float* __restrict__ bhh1,
    const float* __restrict__ W1,
    const float* __restrict__ b1,
    const float* __restrict__ W2,
    const float* __restrict__ b2,
    const short* __restrict__ wih1pk,   // packed bf16 fragments in ws
    float* __restrict__ out)
{
    __shared__ __align__(16) short whh1lds[65536];      // 128 KB
    __shared__ __align__(16) short h0f[2][2048];
    __shared__ __align__(16) short h1f[2][2048];
    __shared__ __align__(16) uint32_t b0wx[8][4][16];   // (wx<<16)|bias0, 2 KB
    __shared__ __align__(16) float    b1t[8][4][16];    // bias1, 2 KB

    const int tid = threadIdx.x;
    const int w   = tid >> 6;        // 0..15
    const int wl  = w & 7;           // wave-in-team; owns units [16wl,16wl+16)
    const bool isL0 = (w < 8);
    const int l = tid & 63;
    const int n = l & 15;            // batch col
    const int q = l >> 4;            // k-group / row-quad
    const int b0 = blockIdx.x * BT;
    const float* xrow = x + (size_t)(b0 + n) * TLEN;

    // ---- stage Whh1 into LDS fragment-ordered (8 frags per thread) ----
    #pragma unroll
    for (int i = 0; i < 8; ++i) {
        const int s2 = tid + i * 1024;
        const int ll = s2 & 63, t = (s2 >> 6) & 3, c = (s2 >> 8) & 3, wv = s2 >> 10;
        const float* p = Whh1 + (t * 128 + wv * 16 + (ll & 15)) * HDIM + c * 32 + (ll >> 4) * 8;
        s16x8 a;
        #pragma unroll
        for (int j = 0; j < 8; ++j) a[j] = (short)f2bf(p[j]);
        *(s16x8*)&whh1lds[s2 * 8] = a;
    }
    // ---- bias tables ----
    if (tid < 512) {
        const int wv = tid >> 6, t = (tid >> 4) & 3, j = tid & 15;
        const int row = t * 128 + wv * 16 + j;
        b0wx[wv][t][j] = ((uint32_t)f2bf(Wih0[row]) << 16) | f2bf(bih0[row] + bhh0[row]);
    } else {
        const int idx = tid - 512;
        const int wv = idx >> 6, t = (idx >> 4) & 3, j = idx & 15;
        const int row = t * 128 + wv * 16 + j;
        b1t[wv][t][j] = bih1[row] + bhh1[row];
    }
    // zero h1[-1] (read at k=0 from h1f[1]) : 1024 u32, one per thread
    ((uint32_t*)h1f[1])[tid] = 0u;

    // B-fragment write slot for this lane's 4 units
    const int u0 = wl * 16 + q * 4;
    const int fragoff = ((u0 >> 5) * 64 + n + 16 * ((u0 >> 3) & 3)) * 8 + (u0 & 7);

#define L0ITER(K, R, W) do {                                                  \
    const int xi_ = (K) + 1;                                                  \
    const float xv_ = xrow[xi_ < TLEN ? xi_ : (TLEN - 1)];                    \
    s16x8 hb_[4];                                                             \
    _Pragma("unroll")                                                         \
    for (int c = 0; c < 4; ++c) hb_[c] = *(const s16x8*)&(R)[(c * 64 + l) * 8]; \
    f32x4 acc_[4];                                                            \
    _Pragma("unroll")                                                         \
    for (int t = 0; t < 4; ++t) {                                             \
        const u32x4 bwt = *(const u32x4*)&b0wx[wl][t][q * 4];                 \
        _Pragma("unroll")                                                     \
        for (int r = 0; r < 4; ++r)                                           \
            acc_[t][r] = fmaf(bfhi(bwt[r]), xv_, bflo(bwt[r]));               \
    }                                                                         \
    __builtin_amdgcn_s_setprio(1);                                            \
    _Pragma("unroll")                                                         \
    for (int c = 0; c < 4; ++c) {                                             \
        _Pragma("unroll")                                                     \
        for (int t = 0; t < 4; ++t)                                           \
            acc_[t] = MFMA16(w0f[c][t], hb_[c], acc_[t]);                     \
    }                                                                         \
    __builtin_amdgcn_s_setprio(0);                                            \
    s16x4 hw_;                                                                \
    _Pragma("unroll")                                                         \
    for (int r = 0; r < 4; ++r) {                                             \
        const float ig = sigmoidf_(acc_[0][r]);                               \
        const float fg = sigmoidf_(acc_[1][r]);                               \
        const float gg = tanhf_(acc_[2][r]);                                  \
        const float og = sigmoidf_(acc_[3][r]);                               \
        const float cc = fmaf(fg, c0v[r], ig * gg);                           \
        c0v[r] = cc;                                                          \
        hw_[r] = (short)f2bf(og * tanhf_(cc));                                \
    }                                                                         \
    *(s16x4*)&(W)[fragoff] = hw_;                                             \
    __syncthreads();                                                          \
} while (0)

#define LOADWI(DST, C) do {                                                   \
    _Pragma("unroll")                                                         \
    for (int t4 = 0; t4 < 4; ++t4)                                            \
        (DST)[t4] = *(const s16x8*)&wih1pk[(((wl * 4 + (C)) * 4 + t4) * 64 + l) * 8]; \
} while (0)

#define L1ITER(K, R0, R1, W1B) do {                                           \
    s16x8 wiA_[4], wiB_[4];                                                   \
    LOADWI(wiA_, 0); LOADWI(wiB_, 1);                                         \
    s16x8 hb0_[4], hb1_[4];                                                   \
    _Pragma("unroll")                                                         \
    for (int c = 0; c < 4; ++c) {                                             \
        hb0_[c] = *(const s16x8*)&(R0)[(c * 64 + l) * 8];                     \
        hb1_[c] = *(const s16x8*)&(R1)[(c * 64 + l) * 8];                     \
    }                                                                         \
    f32x4 acc_[4];                                                            \
    _Pragma("unroll")                                                         \
    for (int t = 0; t < 4; ++t) acc_[t] = *(const f32x4*)&b1t[wl][t][q * 4];  \
    __builtin_amdgcn_s_setprio(1);                                            \
    _Pragma("unroll")                                                         \
    for (int c = 0; c < 4; ++c) {                                             \
        s16x8 wt_[4];                                                         \
        _Pragma("unroll")                                                     \
        for (int t = 0; t < 4; ++t)                                           \
            wt_[t] = *(const s16x8*)&whh1lds[(((wl * 4 + c) * 4 + t) * 64 + l) * 8]; \
        _Pragma("unroll")                                                     \
        for (int t = 0; t < 4; ++t)                                           \
            acc_[t] = MFMA16(wt_[t], hb1_[c], acc_[t]);                       \
    }                                                                         \
    _Pragma("unroll")                                                         \
    for (int t = 0; t < 4; ++t) acc_[t] = MFMA16(wiA_[t], hb0_[0], acc_[t]);  \
    LOADWI(wiA_, 2);                                                          \
    _Pragma("unroll")                                                         \
    for (int t = 0; t < 4; ++t) acc_[t] = MFMA16(wiB_[t], hb0_[1], acc_[t]);  \
    LOADWI(wiB_, 3);                                                          \
    _Pragma("unroll")                                                         \
    for (int t = 0; t < 4; ++t) acc_[t] = MFMA16(wiA_[t], hb0_[2], acc_[t]);  \
    _Pragma("unroll")                                                         \
    for (int t = 0; t < 4; ++t) acc_[t] = MFMA16(wiB_[t], hb0_[3], acc_[t]);  \
    __builtin_amdgcn_s_setprio(0);                                            \
    s16x4 hw_;                                                                \
    _Pragma("unroll")                                                         \
    for (int r = 0; r < 4; ++r) {                                             \
        const float ig = sigmoidf_(acc_[0][r]);                               \
        const float fg = sigmoidf_(acc_[1][r]);                               \
        const float gg = tanhf_(acc_[2][r]);                                  \
        const float og = sigmoidf_(acc_[3][r]);                               \
        const float cc = fmaf(fg, c1v[r], ig * gg);                           \
        c1v[r] = cc;                                                          \
        hw_[r] = (short)f2bf(og * tanhf_(cc));                                \
    }                                                                         \
    *(s16x4*)&(W1B)[fragoff] = hw_;                                           \
    __syncthreads();                                                          \
} while (0)

    if (isL0) {
        // ---- L0 wave: Whh0 fragments for its 16 units (64 regs/AGPRs) ----
        s16x8 w0f[4][4];   // [c][t]
        #pragma unroll
        for (int c = 0; c < 4; ++c) {
            #pragma unroll
            for (int t = 0; t < 4; ++t) {
                const float* p = Whh0 + (t * 128 + wl * 16 + n) * HDIM + c * 32 + q * 8;
                s16x8 a;
                #pragma unroll
                for (int j = 0; j < 8; ++j) a[j] = (short)f2bf(p[j]);
                w0f[c][t] = a;
            }
        }
        float c0v[4] = {0.f, 0.f, 0.f, 0.f};

        __syncthreads();   // staging (b0wx, whh1lds, h1f[1]) visible

        // prologue: h0[0] = pointwise(b0 + wx*x[0]) ; h0[-1]=0 so no MFMA
        {
            const float x0 = xrow[0];
            u32x4 bw0 = *(const u32x4*)&b0wx[wl][0][q * 4];
            u32x4 bw2 = *(const u32x4*)&b0wx[wl][2][q * 4];
            u32x4 bw3 = *(const u32x4*)&b0wx[wl][3][q * 4];
            s16x4 hw;
            #pragma unroll
            for (int r = 0; r < 4; ++r) {
                const float pi = fmaf(bfhi(bw0[r]), x0, bflo(bw0[r]));
                const float pg = fmaf(bfhi(bw2[r]), x0, bflo(bw2[r]));
                const float po = fmaf(bfhi(bw3[r]), x0, bflo(bw3[r]));
                const float ig = sigmoidf_(pi);
                const float gg = tanhf_(pg);
                const float og = sigmoidf_(po);
                const float cc = ig * gg;          // f * c(-1) = 0
                c0v[r] = cc;
                hw[r] = (short)f2bf(og * tanhf_(cc));
            }
            *(s16x4*)&h0f[0][fragoff] = hw;
        }
        __syncthreads();   // h0[0] visible

        #pragma unroll 1
        for (int k = 0; k < TLEN; k += 2) {
            L0ITER(k,     h0f[0], h0f[1]);
            L0ITER(k + 1, h0f[1], h0f[0]);
        }
    } else {
        float c1v[4] = {0.f, 0.f, 0.f, 0.f};
        __syncthreads();   // pairs with L0 post-staging barrier
        __syncthreads();   // pairs with L0 post-prologue barrier

        #pragma unroll 1
        for (int k = 0; k < TLEN; k += 2) {
            L1ITER(k,     h0f[0], h1f[1], h1f[0]);
            L1ITER(k + 1, h0f[1], h1f[0], h1f[1]);
        }
        // h1[511] now in h1f[1]
    }

    // ---- head: aliases whh1lds (all weight reads are behind the last barrier) ----
    float* headH = (float*)whh1lds;          // [16][128] f32 = 8 KB
    float* headL = headH + 16 * HDIM;        // [16][64]  = 4 KB
    if (!isL0) {
        const s16x4 hv = *(const s16x4*)&h1f[1][fragoff];
        f32x4 hf;
        #pragma unroll
        for (int r = 0; r < 4; ++r) hf[r] = bf2f(hv[r]);
        *(f32x4*)&headH[n * HDIM + u0] = hf;
    }
    __syncthreads();

    {   // hidden = relu(h @ W1^T + b1): 1024 threads = 16 batch x 64 hidden
        const int nn = tid >> 6, j = tid & 63;
        float s = b1[j];
        const float* wrow = W1 + j * HDIM;
        const float* hrow = headH + nn * HDIM;
        #pragma unroll
        for (int k = 0; k < HDIM; k += 4) {
            const f32x4 hv = *(const f32x4*)&hrow[k];
            const f32x4 wv = *(const f32x4*)&wrow[k];
            s += hv[0]*wv[0] + hv[1]*wv[1] + hv[2]*wv[2] + hv[3]*wv[3];
        }
        headL[nn * 64 + j] = fmaxf(s, 0.0f);
    }
    __syncthreads();

    if (tid < 128) {
        const int nn = tid >> 3, cls = tid & 7;
        float s = b2[cls];
        const float* wrow = W2 + cls * 64;
        const float* hrow = headL + nn * 64;
        #pragma unroll
        for (int k = 0; k < 64; k += 4) {
            const f32x4 hv = *(const f32x4*)&hrow[k];
            const f32x4 wv = *(const f32x4*)&wrow[k];
            s += hv[0]*wv[0] + hv[1]*wv[1] + hv[2]*wv[2] + hv[3]*wv[3];
        }
        out[(size_t)(b0 + nn) * 8 + cls] = s;
    }
#undef L0ITER
#undef LOADWI
#undef L1ITER
}

// ============================================================================
// Fallback (round-6 kernel, 954 us): used when ws_size < 128 KB.
// ============================================================================
__global__ __launch_bounds__(512, 2) void lstm_fused_kernel(
    const float* __restrict__ x,
    const float* __restrict__ Wih0,
    const float* __restrict__ Whh0,
    const float* __restrict__ bih0,
    const float* __restrict__ bhh0,
    const float* __restrict__ Wih1,
    const float* __restrict__ Whh1,
    const float* __restrict__ bih1,
    const float* __restrict__ bhh1,
    const float* __restrict__ W1,
    const float* __restrict__ b1,
    const float* __restrict__ W2,
    const float* __restrict__ b2,
    float* __restrict__ out)
{
    __shared__ __align__(16) short wh1lds[65536];
    __shared__ __align__(16) short h0f0[2048], h0f1[2048];
    __shared__ __align__(16) short h1f0[2048], h1f1[2048];
    __shared__ __align__(16) float b1lds[4][8][16];

    const int tid = threadIdx.x;
    const int w   = tid >> 6;
    const int wl  = w & 3;
    const bool isL0 = (w < 4);
    const int l = tid & 63;
    const int n = l & 15;
    const int q = l >> 4;
    const int b0 = blockIdx.x * BT;
    const float* xrow = x + (size_t)(b0 + n) * TLEN;

    for (int s2 = tid; s2 < 8192; s2 += 512) {
        const int ll = s2 & 63, t2 = (s2 >> 6) & 7, cc = (s2 >> 9) & 3, wv = s2 >> 11;
        const int row = (t2 >> 1) * 128 + 32 * wv + 16 * (t2 & 1) + (ll & 15);
        const int k0  = cc * 32 + (ll >> 4) * 8;
        const float* p = Whh1 + row * HDIM + k0;
        s16x8 a;
        #pragma unroll
        for (int j = 0; j < 8; ++j) a[j] = (short)f2bf(p[j]);
        *(s16x8*)&wh1lds[s2 * 8] = a;
    }
    {
        const int idx = tid;
        const int wv = idx >> 7, t2 = (idx >> 4) & 7, j = idx & 15;
        const int row = (t2 >> 1) * 128 + 32 * wv + 16 * (t2 & 1) + j;
        b1lds[wv][t2][j] = bih1[row] + bhh1[row];
    }
    for (int s2 = tid; s2 < 1024; s2 += 512) ((uint32_t*)h1f1)[s2] = 0u;

    const int ub0 = 32 * wl + 4 * q;
    const int ub1 = ub0 + 16;
    const int fo0 = ((ub0 >> 5) * 64 + n + 16 * ((ub0 >> 3) & 3)) * 8 + (ub0 & 7);
    const int fo1 = ((ub1 >> 5) * 64 + n + 16 * ((ub1 >> 3) & 3)) * 8 + (ub1 & 7);

#define L0ITER(K, R0, W0) do {                                                \
    const int xi_ = (K) + 1;                                                  \
    const float xv_ = xrow[xi_ < TLEN ? xi_ : (TLEN - 1)];                    \
    s16x8 hb_[4];                                                             \
    _Pragma("unroll")                                                         \
    for (int c = 0; c < 4; ++c) hb_[c] = *(const s16x8*)&(R0)[(c * 64 + l) * 8]; \
    f32x4 a_[8];                                                              \
    _Pragma("unroll")                                                         \
    for (int t2 = 0; t2 < 8; ++t2) {                                          \
        _Pragma("unroll")                                                     \
        for (int r = 0; r < 4; ++r)                                           \
            a_[t2][r] = fmaf(bfhi(bwx[t2][r]), xv_, bflo(bwx[t2][r]));        \
    }                                                                         \
    _Pragma("unroll")                                                         \
    for (int c = 0; c < 4; ++c) {                                             \
        _Pragma("unroll")                                                     \
        for (int t2 = 0; t2 < 8; ++t2)                                        \
            a_[t2] = MFMA16(w0f[c][t2], hb_[c], a_[t2]);                      \
    }                                                                         \
    _Pragma("unroll")                                                         \
    for (int h = 0; h < 2; ++h) {                                             \
        s16x4 hw;                                                             \
        _Pragma("unroll")                                                     \
        for (int r = 0; r < 4; ++r) {                                         \
            const float ig = sigmoidf_(a_[0 + h][r]);                         \
            const float fg = sigmoidf_(a_[2 + h][r]);                         \
            const float gg = tanhf_(a_[4 + h][r]);                            \
            const float og = sigmoidf_(a_[6 + h][r]);                         \
            const float cc = fmaf(fg, c0_[h][r], ig * gg);                    \
            c0_[h][r] = cc;                                                   \
            hw[r] = (short)f2bf(og * tanhf_(cc));                             \
        }                                                                     \
        *(s16x4*)&(W0)[h ? fo1 : fo0] = hw;                                   \
    }                                                                         \
    __syncthreads();                                                          \
} while (0)

#define L1ITER(K, R0, R1, W1) do {                                            \
    s16x8 hb0_[4], hb1_[4];                                                   \
    _Pragma("unroll")                                                         \
    for (int c = 0; c < 4; ++c) {                                             \
        hb0_[c] = *(const s16x8*)&(R0)[(c * 64 + l) * 8];                     \
        hb1_[c] = *(const s16x8*)&(R1)[(c * 64 + l) * 8];                     \
    }                                                                         \
    f32x4 a_[8];                                                              \
    _Pragma("unroll")                                                         \
    for (int t2 = 0; t2 < 8; ++t2)                                            \
        a_[t2] = *(const f32x4*)&b1lds[wl][t2][q * 4];                        \
    _Pragma("unroll")                                                         \
    for (int c = 0; c < 4; ++c) {                                             \
        _Pragma("unroll")                                                     \
        for (int t2 = 0; t2 < 8; ++t2)                                        \
            a_[t2] = MFMA16(wi1f[c][t2], hb0_[c], a_[t2]);                    \
    }                                                                         \
    _Pragma("unroll")                                                         \
    for (int c = 0; c < 4; ++c) {                                             \
        s16x8 wt_[8];                                                         \
        _Pragma("unroll")                                                     \
        for (int t2 = 0; t2 < 8; ++t2)                                        \
            wt_[t2] = *(const s16x8*)&wh1lds[(((wl * 4 + c) * 8 + t2) * 64 + l) * 8]; \
        _Pragma("unroll")                                                     \
        for (int t2 = 0; t2 < 8; ++t2)                                        \
            a_[t2] = MFMA16(wt_[t2], hb1_[c], a_[t2]);                        \
    }                                                                         \
    _Pragma("unroll")                                                         \
    for (int h = 0; h < 2; ++h) {                                             \
        s16x4 hw;                                                             \
        _Pragma("unroll")                                                     \
        for (int r = 0; r < 4; ++r) {                                         \
            const float ig = sigmoidf_(a_[0 + h][r]);                         \
            const float fg = sigmoidf_(a_[2 + h][r]);                         \
            const float gg = tanhf_(a_[4 + h][r]);                            \
            const float og = sigmoidf_(a_[6 + h][r]);                         \
            const float cc = fmaf(fg, c1_[h][r], ig * gg);                    \
            c1_[h][r] = cc;                                                   \
            hw[r] = (short)f2bf(og * tanhf_(cc));                             \
        }                                                                     \
        *(s16x4*)&(W1)[h ? fo1 : fo0] = hw;                                   \
    }                                                                         \
    __syncthreads();                                                          \
} while (0)

    if (isL0) {
        s16x8 w0f[4][8];
        #pragma unroll
        for (int c = 0; c < 4; ++c) {
            #pragma unroll
            for (int t2 = 0; t2 < 8; ++t2) {
                const int row = (t2 >> 1) * 128 + 32 * wl + 16 * (t2 & 1) + n;
                const int k0 = c * 32 + q * 8;
                const float* p = Whh0 + row * HDIM + k0;
                s16x8 a;
                #pragma unroll
                for (int j = 0; j < 8; ++j) a[j] = (short)f2bf(p[j]);
                w0f[c][t2] = a;
            }
        }
        u32x4 bwx[8];
        #pragma unroll
        for (int t2 = 0; t2 < 8; ++t2) {
            #pragma unroll
            for (int r = 0; r < 4; ++r) {
                const int row = (t2 >> 1) * 128 + 32 * wl + 16 * (t2 & 1) + 4 * q + r;
                bwx[t2][r] = ((uint32_t)f2bf(Wih0[row]) << 16) | f2bf(bih0[row] + bhh0[row]);
            }
        }
        float c0_[2][4] = {{0.f,0.f,0.f,0.f},{0.f,0.f,0.f,0.f}};
        {
            const float x0 = xrow[0];
            #pragma unroll
            for (int h = 0; h < 2; ++h) {
                s16x4 hw;
                #pragma unroll
                for (int r = 0; r < 4; ++r) {
                    const float pi = fmaf(bfhi(bwx[0 + h][r]), x0, bflo(bwx[0 + h][r]));
                    const float pg = fmaf(bfhi(bwx[4 + h][r]), x0, bflo(bwx[4 + h][r]));
                    const float po = fmaf(bfhi(bwx[6 + h][r]), x0, bflo(bwx[6 + h][r]));
                    const float ig = sigmoidf_(pi);
                    const float gg = tanhf_(pg);
                    const float og = sigmoidf_(po);
                    const float cc = ig * gg;
                    c0_[h][r] = cc;
                    hw[r] = (short)f2bf(og * tanhf_(cc));
                }
                *(s16x4*)&h0f0[h ? fo1 : fo0] = hw;
            }
        }
        __syncthreads();
        #pragma unroll 1
        for (int k = 0; k < TLEN; k += 2) {
            L0ITER(k,     h0f0, h0f1);
            L0ITER(k + 1, h0f1, h0f0);
        }
    } else {
        s16x8 wi1f[4][8];
        #pragma unroll
        for (int c = 0; c < 4; ++c) {
            #pragma unroll
            for (int t2 = 0; t2 < 8; ++t2) {
                const int row = (t2 >> 1) * 128 + 32 * wl + 16 * (t2 & 1) + n;
                const int k0 = c * 32 + q * 8;
                const float* p = Wih1 + row * HDIM + k0;
                s16x8 a;
                #pragma unroll
                for (int j = 0; j < 8; ++j) a[j] = (short)f2bf(p[j]);
                wi1f[c][t2] = a;
            }
        }
        float c1_[2][4] = {{0.f,0.f,0.f,0.f},{0.f,0.f,0.f,0.f}};
        __syncthreads();
        #pragma unroll 1
        for (int k = 0; k < TLEN; k += 2) {
            L1ITER(k,     h0f0, h1f1, h1f0);
            L1ITER(k + 1, h0f1, h1f0, h1f1);
        }
    }

    __syncthreads();

    float* headH = (float*)wh1lds;
    float* headL = headH + 16 * HDIM;
    if (!isL0) {
        #pragma unroll
        for (int h = 0; h < 2; ++h) {
            const s16x4 hv = *(const s16x4*)&h1f1[h ? fo1 : fo0];
            f32x4 hf;
            #pragma unroll
            for (int r = 0; r < 4; ++r) hf[r] = bf2f(hv[r]);
            *(f32x4*)&headH[n * HDIM + (h ? ub1 : ub0)] = hf;
        }
    }
    __syncthreads();

    #pragma unroll
    for (int rep = 0; rep < 2; ++rep) {
        const int idx = tid + rep * 512;
        const int nn = idx >> 6, j = idx & 63;
        float s = b1[j];
        const float* wrow = W1 + j * HDIM;
        const float* hrow = headH + nn * HDIM;
        #pragma unroll
        for (int k = 0; k < HDIM; k += 4) {
            const f32x4 hv = *(const f32x4*)&hrow[k];
            const f32x4 wv = *(const f32x4*)&wrow[k];
            s += hv[0]*wv[0] + hv[1]*wv[1] + hv[2]*wv[2] + hv[3]*wv[3];
        }
        headL[nn * 64 + j] = fmaxf(s, 0.0f);
    }
    __syncthreads();

    if (tid < 128) {
        const int nn = tid >> 3, cls = tid & 7;
        float s = b2[cls];
        const float* wrow = W2 + cls * 64;
        const float* hrow = headL + nn * 64;
        #pragma unroll
        for (int k = 0; k < 64; k += 4) {
            const f32x4 hv = *(const f32x4*)&hrow[k];
            const f32x4 wv = *(const f32x4*)&wrow[k];
            s += hv[0]*wv[0] + hv[1]*wv[1] + hv[2]*wv[2] + hv[3]*wv[3];
        }
        out[(size_t)(b0 + nn) * 8 + cls] = s;
    }
#undef L0ITER
#undef L1ITER
}

extern "C" void kernel_launch(void* const* d_in, const int* in_sizes, int n_in,
                              void* d_out, int out_size, void* d_ws, size_t ws_size,
                              hipStream_t stream) {
    const float* x    = (const float*)d_in[0];
    const float* Wih0 = (const float*)d_in[1];
    const float* Whh0 = (const float*)d_in[2];
    const float* bih0 = (const float*)d_in[3];
    const float* bhh0 = (const float*)d_in[4];
    const float* Wih1 = (const float*)d_in[5];
    const float* Whh1 = (const float*)d_in[6];
    const float* bih1 = (const float*)d_in[7];
    const float* bhh1 = (const float*)d_in[8];
    const float* W1   = (const float*)d_in[9];
    const float* b1   = (const float*)d_in[10];
    const float* W2   = (const float*)d_in[11];
    const float* b2   = (const float*)d_in[12];
    float* outp = (float*)d_out;

    const size_t PACK_BYTES = (size_t)512 * 128 * sizeof(short);   // 128 KB

    if (ws_size >= PACK_BYTES) {
        short* wih1pk = (short*)d_ws;
        pack_wih1_kernel<<<8, 1024, 0, stream>>>(Wih1, wih1pk);
        lstm_mega_kernel<<<128, 1024, 0, stream>>>(
            x, Wih0, Whh0, bih0, bhh0, Whh1, bih1, bhh1,
            W1, b1, W2, b2, wih1pk, outp);
    } else {
        lstm_fused_kernel<<<128, 512, 0, stream>>>(
            x, Wih0, Whh0, bih0, bhh0, Wih1, Whh1, bih1, bhh1,
            W1, b1, W2, b2, outp);
    }
}

// Round 17
// 888.004 us; speedup vs baseline: 2.1500x; 1.1192x over previous
//
#include <hip/hip_runtime.h>
#include <stdint.h>

typedef float f32x4 __attribute__((ext_vector_type(4)));
typedef short s16x8 __attribute__((ext_vector_type(8)));
typedef short s16x4 __attribute__((ext_vector_type(4)));
typedef uint32_t u32x4 __attribute__((ext_vector_type(4)));

#define HDIM 128
#define TLEN 512
#define BT 16

__device__ __forceinline__ unsigned short f2bf(float f) {
    union { float f; uint32_t u; } v; v.f = f;
    uint32_t r = v.u + 0x7FFFu + ((v.u >> 16) & 1u);
    return (unsigned short)(r >> 16);
}
__device__ __forceinline__ float bfhi(uint32_t u){ union{uint32_t u;float f;}v; v.u = u & 0xFFFF0000u; return v.f; }
__device__ __forceinline__ float bflo(uint32_t u){ union{uint32_t u;float f;}v; v.u = u << 16; return v.f; }
__device__ __forceinline__ float bf2f(short s){ union{uint32_t u;float f;}v; v.u = ((uint32_t)(unsigned short)s) << 16; return v.f; }

__device__ __forceinline__ float sigmoidf_(float x){
    float e = __expf(-x);
    return __builtin_amdgcn_rcpf(1.0f + e);
}
__device__ __forceinline__ float tanhf_(float x){
    float e = __expf(2.0f * x);
    return 1.0f - 2.0f * __builtin_amdgcn_rcpf(1.0f + e);
}

#define MFMA16(A, B, C) __builtin_amdgcn_mfma_f32_16x16x32_bf16((A), (B), (C), 0, 0, 0)

// ============================================================================
// Pack kernel: Wih1 (f32, 512x128) -> bf16 fragment-ordered in d_ws.
// Fragment F(wl,c,t) = (wl*4+c)*4+t ; lane l ; shorts at (F*64+l)*8.
// ============================================================================
__global__ __launch_bounds__(1024) void pack_wih1_kernel(
    const float* __restrict__ Wih1, short* __restrict__ dst)
{
    const int s2 = blockIdx.x * 1024 + threadIdx.x;   // 0..8191
    const int ll = s2 & 63;
    const int t  = (s2 >> 6) & 3;
    const int c  = (s2 >> 8) & 3;
    const int wl = s2 >> 10;
    const float* p = Wih1 + (t * 128 + wl * 16 + (ll & 15)) * HDIM + c * 32 + (ll >> 4) * 8;
    s16x8 a;
    #pragma unroll
    for (int j = 0; j < 8; ++j) a[j] = (short)f2bf(p[j]);
    *(s16x8*)&dst[s2 * 8] = a;
}

// ============================================================================
// Main (round-11 structure, proven 891 us, NO setprio — r16 showed it hurts):
// 128 blocks x 1024 threads (16 waves, 4/SIMD). Teams of 8 waves:
// L0 (w<8): Whh0 in regs (64/wave). L1 (w>=8): Whh1 from LDS, Wih1 from
// global L2 (packed bf16 in ws). 1 barrier/step.
// ============================================================================
__global__ __launch_bounds__(1024, 4) void lstm_mega_kernel(
    const float* __restrict__ x,
    const float* __restrict__ Wih0,
    const float* __restrict__ Whh0,
    const float* __restrict__ bih0,
    const float* __restrict__ bhh0,
    const float* __restrict__ Whh1,
    const float* __restrict__ bih1,
    const float* __restrict__ bhh1,
    const float* __restrict__ W1,
    const float* __restrict__ b1,
    const float* __restrict__ W2,
    const float* __restrict__ b2,
    const short* __restrict__ wih1pk,   // packed bf16 fragments in ws
    float* __restrict__ out)
{
    __shared__ __align__(16) short whh1lds[65536];      // 128 KB
    __shared__ __align__(16) short h0f[2][2048];
    __shared__ __align__(16) short h1f[2][2048];
    __shared__ __align__(16) uint32_t b0wx[8][4][16];   // (wx<<16)|bias0, 2 KB
    __shared__ __align__(16) float    b1t[8][4][16];    // bias1, 2 KB

    const int tid = threadIdx.x;
    const int w   = tid >> 6;        // 0..15
    const int wl  = w & 7;           // wave-in-team; owns units [16wl,16wl+16)
    const bool isL0 = (w < 8);
    const int l = tid & 63;
    const int n = l & 15;            // batch col
    const int q = l >> 4;            // k-group / row-quad
    const int b0 = blockIdx.x * BT;
    const float* xrow = x + (size_t)(b0 + n) * TLEN;

    // ---- stage Whh1 into LDS fragment-ordered (8 frags per thread) ----
    #pragma unroll
    for (int i = 0; i < 8; ++i) {
        const int s2 = tid + i * 1024;
        const int ll = s2 & 63, t = (s2 >> 6) & 3, c = (s2 >> 8) & 3, wv = s2 >> 10;
        const float* p = Whh1 + (t * 128 + wv * 16 + (ll & 15)) * HDIM + c * 32 + (ll >> 4) * 8;
        s16x8 a;
        #pragma unroll
        for (int j = 0; j < 8; ++j) a[j] = (short)f2bf(p[j]);
        *(s16x8*)&whh1lds[s2 * 8] = a;
    }
    // ---- bias tables ----
    if (tid < 512) {
        const int wv = tid >> 6, t = (tid >> 4) & 3, j = tid & 15;
        const int row = t * 128 + wv * 16 + j;
        b0wx[wv][t][j] = ((uint32_t)f2bf(Wih0[row]) << 16) | f2bf(bih0[row] + bhh0[row]);
    } else {
        const int idx = tid - 512;
        const int wv = idx >> 6, t = (idx >> 4) & 3, j = idx & 15;
        const int row = t * 128 + wv * 16 + j;
        b1t[wv][t][j] = bih1[row] + bhh1[row];
    }
    // zero h1[-1] (read at k=0 from h1f[1]) : 1024 u32, one per thread
    ((uint32_t*)h1f[1])[tid] = 0u;

    // B-fragment write slot for this lane's 4 units
    const int u0 = wl * 16 + q * 4;
    const int fragoff = ((u0 >> 5) * 64 + n + 16 * ((u0 >> 3) & 3)) * 8 + (u0 & 7);

#define L0ITER(K, R, W) do {                                                  \
    const int xi_ = (K) + 1;                                                  \
    const float xv_ = xrow[xi_ < TLEN ? xi_ : (TLEN - 1)];                    \
    s16x8 hb_[4];                                                             \
    _Pragma("unroll")                                                         \
    for (int c = 0; c < 4; ++c) hb_[c] = *(const s16x8*)&(R)[(c * 64 + l) * 8]; \
    f32x4 acc_[4];                                                            \
    _Pragma("unroll")                                                         \
    for (int t = 0; t < 4; ++t) {                                             \
        const u32x4 bwt = *(const u32x4*)&b0wx[wl][t][q * 4];                 \
        _Pragma("unroll")                                                     \
        for (int r = 0; r < 4; ++r)                                           \
            acc_[t][r] = fmaf(bfhi(bwt[r]), xv_, bflo(bwt[r]));               \
    }                                                                         \
    _Pragma("unroll")                                                         \
    for (int c = 0; c < 4; ++c) {                                             \
        _Pragma("unroll")                                                     \
        for (int t = 0; t < 4; ++t)                                           \
            acc_[t] = MFMA16(w0f[c][t], hb_[c], acc_[t]);                     \
    }                                                                         \
    s16x4 hw_;                                                                \
    _Pragma("unroll")                                                         \
    for (int r = 0; r < 4; ++r) {                                             \
        const float ig = sigmoidf_(acc_[0][r]);                               \
        const float fg = sigmoidf_(acc_[1][r]);                               \
        const float gg = tanhf_(acc_[2][r]);                                  \
        const float og = sigmoidf_(acc_[3][r]);                               \
        const float cc = fmaf(fg, c0v[r], ig * gg);                           \
        c0v[r] = cc;                                                          \
        hw_[r] = (short)f2bf(og * tanhf_(cc));                                \
    }                                                                         \
    *(s16x4*)&(W)[fragoff] = hw_;                                             \
    __syncthreads();                                                          \
} while (0)

#define LOADWI(DST, C) do {                                                   \
    _Pragma("unroll")                                                         \
    for (int t4 = 0; t4 < 4; ++t4)                                            \
        (DST)[t4] = *(const s16x8*)&wih1pk[(((wl * 4 + (C)) * 4 + t4) * 64 + l) * 8]; \
} while (0)

#define L1ITER(K, R0, R1, W1B) do {                                           \
    s16x8 wiA_[4], wiB_[4];                                                   \
    LOADWI(wiA_, 0); LOADWI(wiB_, 1);                                         \
    s16x8 hb0_[4], hb1_[4];                                                   \
    _Pragma("unroll")                                                         \
    for (int c = 0; c < 4; ++c) {                                             \
        hb0_[c] = *(const s16x8*)&(R0)[(c * 64 + l) * 8];                     \
        hb1_[c] = *(const s16x8*)&(R1)[(c * 64 + l) * 8];                     \
    }                                                                         \
    f32x4 acc_[4];                                                            \
    _Pragma("unroll")                                                         \
    for (int t = 0; t < 4; ++t) acc_[t] = *(const f32x4*)&b1t[wl][t][q * 4];  \
    _Pragma("unroll")                                                         \
    for (int c = 0; c < 4; ++c) {                                             \
        s16x8 wt_[4];                                                         \
        _Pragma("unroll")                                                     \
        for (int t = 0; t < 4; ++t)                                           \
            wt_[t] = *(const s16x8*)&whh1lds[(((wl * 4 + c) * 4 + t) * 64 + l) * 8]; \
        _Pragma("unroll")                                                     \
        for (int t = 0; t < 4; ++t)                                           \
            acc_[t] = MFMA16(wt_[t], hb1_[c], acc_[t]);                       \
    }                                                                         \
    _Pragma("unroll")                                                         \
    for (int t = 0; t < 4; ++t) acc_[t] = MFMA16(wiA_[t], hb0_[0], acc_[t]);  \
    LOADWI(wiA_, 2);                                                          \
    _Pragma("unroll")                                                         \
    for (int t = 0; t < 4; ++t) acc_[t] = MFMA16(wiB_[t], hb0_[1], acc_[t]);  \
    LOADWI(wiB_, 3);                                                          \
    _Pragma("unroll")                                                         \
    for (int t = 0; t < 4; ++t) acc_[t] = MFMA16(wiA_[t], hb0_[2], acc_[t]);  \
    _Pragma("unroll")                                                         \
    for (int t = 0; t < 4; ++t) acc_[t] = MFMA16(wiB_[t], hb0_[3], acc_[t]);  \
    s16x4 hw_;                                                                \
    _Pragma("unroll")                                                         \
    for (int r = 0; r < 4; ++r) {                                             \
        const float ig = sigmoidf_(acc_[0][r]);                               \
        const float fg = sigmoidf_(acc_[1][r]);                               \
        const float gg = tanhf_(acc_[2][r]);                                  \
        const float og = sigmoidf_(acc_[3][r]);                               \
        const float cc = fmaf(fg, c1v[r], ig * gg);                           \
        c1v[r] = cc;                                                          \
        hw_[r] = (short)f2bf(og * tanhf_(cc));                                \
    }                                                                         \
    *(s16x4*)&(W1B)[fragoff] = hw_;                                           \
    __syncthreads();                                                          \
} while (0)

    if (isL0) {
        // ---- L0 wave: Whh0 fragments for its 16 units (64 regs) ----
        s16x8 w0f[4][4];   // [c][t]
        #pragma unroll
        for (int c = 0; c < 4; ++c) {
            #pragma unroll
            for (int t = 0; t < 4; ++t) {
                const float* p = Whh0 + (t * 128 + wl * 16 + n) * HDIM + c * 32 + q * 8;
                s16x8 a;
                #pragma unroll
                for (int j = 0; j < 8; ++j) a[j] = (short)f2bf(p[j]);
                w0f[c][t] = a;
            }
        }
        float c0v[4] = {0.f, 0.f, 0.f, 0.f};

        __syncthreads();   // staging (b0wx, whh1lds, h1f[1]) visible

        // prologue: h0[0] = pointwise(b0 + wx*x[0]) ; h0[-1]=0 so no MFMA
        {
            const float x0 = xrow[0];
            u32x4 bw0 = *(const u32x4*)&b0wx[wl][0][q * 4];
            u32x4 bw2 = *(const u32x4*)&b0wx[wl][2][q * 4];
            u32x4 bw3 = *(const u32x4*)&b0wx[wl][3][q * 4];
            s16x4 hw;
            #pragma unroll
            for (int r = 0; r < 4; ++r) {
                const float pi = fmaf(bfhi(bw0[r]), x0, bflo(bw0[r]));
                const float pg = fmaf(bfhi(bw2[r]), x0, bflo(bw2[r]));
                const float po = fmaf(bfhi(bw3[r]), x0, bflo(bw3[r]));
                const float ig = sigmoidf_(pi);
                const float gg = tanhf_(pg);
                const float og = sigmoidf_(po);
                const float cc = ig * gg;          // f * c(-1) = 0
                c0v[r] = cc;
                hw[r] = (short)f2bf(og * tanhf_(cc));
            }
            *(s16x4*)&h0f[0][fragoff] = hw;
        }
        __syncthreads();   // h0[0] visible

        #pragma unroll 1
        for (int k = 0; k < TLEN; k += 2) {
            L0ITER(k,     h0f[0], h0f[1]);
            L0ITER(k + 1, h0f[1], h0f[0]);
        }
    } else {
        float c1v[4] = {0.f, 0.f, 0.f, 0.f};
        __syncthreads();   // pairs with L0 post-staging barrier
        __syncthreads();   // pairs with L0 post-prologue barrier

        #pragma unroll 1
        for (int k = 0; k < TLEN; k += 2) {
            L1ITER(k,     h0f[0], h1f[1], h1f[0]);
            L1ITER(k + 1, h0f[1], h1f[0], h1f[1]);
        }
        // h1[511] now in h1f[1]
    }

    // ---- head: aliases whh1lds (all weight reads are behind the last barrier) ----
    float* headH = (float*)whh1lds;          // [16][128] f32 = 8 KB
    float* headL = headH + 16 * HDIM;        // [16][64]  = 4 KB
    if (!isL0) {
        const s16x4 hv = *(const s16x4*)&h1f[1][fragoff];
        f32x4 hf;
        #pragma unroll
        for (int r = 0; r < 4; ++r) hf[r] = bf2f(hv[r]);
        *(f32x4*)&headH[n * HDIM + u0] = hf;
    }
    __syncthreads();

    {   // hidden = relu(h @ W1^T + b1): 1024 threads = 16 batch x 64 hidden
        const int nn = tid >> 6, j = tid & 63;
        float s = b1[j];
        const float* wrow = W1 + j * HDIM;
        const float* hrow = headH + nn * HDIM;
        #pragma unroll
        for (int k = 0; k < HDIM; k += 4) {
            const f32x4 hv = *(const f32x4*)&hrow[k];
            const f32x4 wv = *(const f32x4*)&wrow[k];
            s += hv[0]*wv[0] + hv[1]*wv[1] + hv[2]*wv[2] + hv[3]*wv[3];
        }
        headL[nn * 64 + j] = fmaxf(s, 0.0f);
    }
    __syncthreads();

    if (tid < 128) {
        const int nn = tid >> 3, cls = tid & 7;
        float s = b2[cls];
        const float* wrow = W2 + cls * 64;
        const float* hrow = headL + nn * 64;
        #pragma unroll
        for (int k = 0; k < 64; k += 4) {
            const f32x4 hv = *(const f32x4*)&hrow[k];
            const f32x4 wv = *(const f32x4*)&wrow[k];
            s += hv[0]*wv[0] + hv[1]*wv[1] + hv[2]*wv[2] + hv[3]*wv[3];
        }
        out[(size_t)(b0 + nn) * 8 + cls] = s;
    }
#undef L0ITER
#undef LOADWI
#undef L1ITER
}

// ============================================================================
// Fallback (round-6 kernel, 954 us): used when ws_size < 128 KB.
// ============================================================================
__global__ __launch_bounds__(512, 2) void lstm_fused_kernel(
    const float* __restrict__ x,
    const float* __restrict__ Wih0,
    const float* __restrict__ Whh0,
    const float* __restrict__ bih0,
    const float* __restrict__ bhh0,
    const float* __restrict__ Wih1,
    const float* __restrict__ Whh1,
    const float* __restrict__ bih1,
    const float* __restrict__ bhh1,
    const float* __restrict__ W1,
    const float* __restrict__ b1,
    const float* __restrict__ W2,
    const float* __restrict__ b2,
    float* __restrict__ out)
{
    __shared__ __align__(16) short wh1lds[65536];
    __shared__ __align__(16) short h0f0[2048], h0f1[2048];
    __shared__ __align__(16) short h1f0[2048], h1f1[2048];
    __shared__ __align__(16) float b1lds[4][8][16];

    const int tid = threadIdx.x;
    const int w   = tid >> 6;
    const int wl  = w & 3;
    const bool isL0 = (w < 4);
    const int l = tid & 63;
    const int n = l & 15;
    const int q = l >> 4;
    const int b0 = blockIdx.x * BT;
    const float* xrow = x + (size_t)(b0 + n) * TLEN;

    for (int s2 = tid; s2 < 8192; s2 += 512) {
        const int ll = s2 & 63, t2 = (s2 >> 6) & 7, cc = (s2 >> 9) & 3, wv = s2 >> 11;
        const int row = (t2 >> 1) * 128 + 32 * wv + 16 * (t2 & 1) + (ll & 15);
        const int k0  = cc * 32 + (ll >> 4) * 8;
        const float* p = Whh1 + row * HDIM + k0;
        s16x8 a;
        #pragma unroll
        for (int j = 0; j < 8; ++j) a[j] = (short)f2bf(p[j]);
        *(s16x8*)&wh1lds[s2 * 8] = a;
    }
    {
        const int idx = tid;
        const int wv = idx >> 7, t2 = (idx >> 4) & 7, j = idx & 15;
        const int row = (t2 >> 1) * 128 + 32 * wv + 16 * (t2 & 1) + j;
        b1lds[wv][t2][j] = bih1[row] + bhh1[row];
    }
    for (int s2 = tid; s2 < 1024; s2 += 512) ((uint32_t*)h1f1)[s2] = 0u;

    const int ub0 = 32 * wl + 4 * q;
    const int ub1 = ub0 + 16;
    const int fo0 = ((ub0 >> 5) * 64 + n + 16 * ((ub0 >> 3) & 3)) * 8 + (ub0 & 7);
    const int fo1 = ((ub1 >> 5) * 64 + n + 16 * ((ub1 >> 3) & 3)) * 8 + (ub1 & 7);

#define L0ITER(K, R0, W0) do {                                                \
    const int xi_ = (K) + 1;                                                  \
    const float xv_ = xrow[xi_ < TLEN ? xi_ : (TLEN - 1)];                    \
    s16x8 hb_[4];                                                             \
    _Pragma("unroll")                                                         \
    for (int c = 0; c < 4; ++c) hb_[c] = *(const s16x8*)&(R0)[(c * 64 + l) * 8]; \
    f32x4 a_[8];                                                              \
    _Pragma("unroll")                                                         \
    for (int t2 = 0; t2 < 8; ++t2) {                                          \
        _Pragma("unroll")                                                     \
        for (int r = 0; r < 4; ++r)                                           \
            a_[t2][r] = fmaf(bfhi(bwx[t2][r]), xv_, bflo(bwx[t2][r]));        \
    }                                                                         \
    _Pragma("unroll")                                                         \
    for (int c = 0; c < 4; ++c) {                                             \
        _Pragma("unroll")                                                     \
        for (int t2 = 0; t2 < 8; ++t2)                                        \
            a_[t2] = MFMA16(w0f[c][t2], hb_[c], a_[t2]);                      \
    }                                                                         \
    _Pragma("unroll")                                                         \
    for (int h = 0; h < 2; ++h) {                                             \
        s16x4 hw;                                                             \
        _Pragma("unroll")                                                     \
        for (int r = 0; r < 4; ++r) {                                         \
            const float ig = sigmoidf_(a_[0 + h][r]);                         \
            const float fg = sigmoidf_(a_[2 + h][r]);                         \
            const float gg = tanhf_(a_[4 + h][r]);                            \
            const float og = sigmoidf_(a_[6 + h][r]);                         \
            const float cc = fmaf(fg, c0_[h][r], ig * gg);                    \
            c0_[h][r] = cc;                                                   \
            hw[r] = (short)f2bf(og * tanhf_(cc));                             \
        }                                                                     \
        *(s16x4*)&(W0)[h ? fo1 : fo0] = hw;                                   \
    }                                                                         \
    __syncthreads();                                                          \
} while (0)

#define L1ITER(K, R0, R1, W1) do {                                            \
    s16x8 hb0_[4], hb1_[4];                                                   \
    _Pragma("unroll")                                                         \
    for (int c = 0; c < 4; ++c) {                                             \
        hb0_[c] = *(const s16x8*)&(R0)[(c * 64 + l) * 8];                     \
        hb1_[c] = *(const s16x8*)&(R1)[(c * 64 + l) * 8];                     \
    }                                                                         \
    f32x4 a_[8];                                                              \
    _Pragma("unroll")                                                         \
    for (int t2 = 0; t2 < 8; ++t2)                                            \
        a_[t2] = *(const f32x4*)&b1lds[wl][t2][q * 4];                        \
    _Pragma("unroll")                                                         \
    for (int c = 0; c < 4; ++c) {                                             \
        _Pragma("unroll")                                                     \
        for (int t2 = 0; t2 < 8; ++t2)                                        \
            a_[t2] = MFMA16(wi1f[c][t2], hb0_[c], a_[t2]);                    \
    }                                                                         \
    _Pragma("unroll")                                                         \
    for (int c = 0; c < 4; ++c) {                                             \
        s16x8 wt_[8];                                                         \
        _Pragma("unroll")                                                     \
        for (int t2 = 0; t2 < 8; ++t2)                                        \
            wt_[t2] = *(const s16x8*)&wh1lds[(((wl * 4 + c) * 8 + t2) * 64 + l) * 8]; \
        _Pragma("unroll")                                                     \
        for (int t2 = 0; t2 < 8; ++t2)                                        \
            a_[t2] = MFMA16(wt_[t2], hb1_[c], a_[t2]);                        \
    }                                                                         \
    _Pragma("unroll")                                                         \
    for (int h = 0; h < 2; ++h) {                                             \
        s16x4 hw;                                                             \
        _Pragma("unroll")                                                     \
        for (int r = 0; r < 4; ++r) {                                         \
            const float ig = sigmoidf_(a_[0 + h][r]);                         \
            const float fg = sigmoidf_(a_[2 + h][r]);                         \
            const float gg = tanhf_(a_[4 + h][r]);                            \
            const float og = sigmoidf_(a_[6 + h][r]);                         \
            const float cc = fmaf(fg, c1_[h][r], ig * gg);                    \
            c1_[h][r] = cc;                                                   \
            hw[r] = (short)f2bf(og * tanhf_(cc));                             \
        }                                                                     \
        *(s16x4*)&(W1)[h ? fo1 : fo0] = hw;                                   \
    }                                                                         \
    __syncthreads();                                                          \
} while (0)

    if (isL0) {
        s16x8 w0f[4][8];
        #pragma unroll
        for (int c = 0; c < 4; ++c) {
            #pragma unroll
            for (int t2 = 0; t2 < 8; ++t2) {
                const int row = (t2 >> 1) * 128 + 32 * wl + 16 * (t2 & 1) + n;
                const int k0 = c * 32 + q * 8;
                const float* p = Whh0 + row * HDIM + k0;
                s16x8 a;
                #pragma unroll
                for (int j = 0; j < 8; ++j) a[j] = (short)f2bf(p[j]);
                w0f[c][t2] = a;
            }
        }
        u32x4 bwx[8];
        #pragma unroll
        for (int t2 = 0; t2 < 8; ++t2) {
            #pragma unroll
            for (int r = 0; r < 4; ++r) {
                const int row = (t2 >> 1) * 128 + 32 * wl + 16 * (t2 & 1) + 4 * q + r;
                bwx[t2][r] = ((uint32_t)f2bf(Wih0[row]) << 16) | f2bf(bih0[row] + bhh0[row]);
            }
        }
        float c0_[2][4] = {{0.f,0.f,0.f,0.f},{0.f,0.f,0.f,0.f}};
        {
            const float x0 = xrow[0];
            #pragma unroll
            for (int h = 0; h < 2; ++h) {
                s16x4 hw;
                #pragma unroll
                for (int r = 0; r < 4; ++r) {
                    const float pi = fmaf(bfhi(bwx[0 + h][r]), x0, bflo(bwx[0 + h][r]));
                    const float pg = fmaf(bfhi(bwx[4 + h][r]), x0, bflo(bwx[4 + h][r]));
                    const float po = fmaf(bfhi(bwx[6 + h][r]), x0, bflo(bwx[6 + h][r]));
                    const float ig = sigmoidf_(pi);
                    const float gg = tanhf_(pg);
                    const float og = sigmoidf_(po);
                    const float cc = ig * gg;
                    c0_[h][r] = cc;
                    hw[r] = (short)f2bf(og * tanhf_(cc));
                }
                *(s16x4*)&h0f0[h ? fo1 : fo0] = hw;
            }
        }
        __syncthreads();
        #pragma unroll 1
        for (int k = 0; k < TLEN; k += 2) {
            L0ITER(k,     h0f0, h0f1);
            L0ITER(k + 1, h0f1, h0f0);
        }
    } else {
        s16x8 wi1f[4][8];
        #pragma unroll
        for (int c = 0; c < 4; ++c) {
            #pragma unroll
            for (int t2 = 0; t2 < 8; ++t2) {
                const int row = (t2 >> 1) * 128 + 32 * wl + 16 * (t2 & 1) + n;
                const int k0 = c * 32 + q * 8;
                const float* p = Wih1 + row * HDIM + k0;
                s16x8 a;
                #pragma unroll
                for (int j = 0; j < 8; ++j) a[j] = (short)f2bf(p[j]);
                wi1f[c][t2] = a;
            }
        }
        float c1_[2][4] = {{0.f,0.f,0.f,0.f},{0.f,0.f,0.f,0.f}};
        __syncthreads();
        #pragma unroll 1
        for (int k = 0; k < TLEN; k += 2) {
            L1ITER(k,     h0f0, h1f1, h1f0);
            L1ITER(k + 1, h0f1, h1f0, h1f1);
        }
    }

    __syncthreads();

    float* headH = (float*)wh1lds;
    float* headL = headH + 16 * HDIM;
    if (!isL0) {
        #pragma unroll
        for (int h = 0; h < 2; ++h) {
            const s16x4 hv = *(const s16x4*)&h1f1[h ? fo1 : fo0];
            f32x4 hf;
            #pragma unroll
            for (int r = 0; r < 4; ++r) hf[r] = bf2f(hv[r]);
            *(f32x4*)&headH[n * HDIM + (h ? ub1 : ub0)] = hf;
        }
    }
    __syncthreads();

    #pragma unroll
    for (int rep = 0; rep < 2; ++rep) {
        const int idx = tid + rep * 512;
        const int nn = idx >> 6, j = idx & 63;
        float s = b1[j];
        const float* wrow = W1 + j * HDIM;
        const float* hrow = headH + nn * HDIM;
        #pragma unroll
        for (int k = 0; k < HDIM; k += 4) {
            const f32x4 hv = *(const f32x4*)&hrow[k];
            const f32x4 wv = *(const f32x4*)&wrow[k];
            s += hv[0]*wv[0] + hv[1]*wv[1] + hv[2]*wv[2] + hv[3]*wv[3];
        }
        headL[nn * 64 + j] = fmaxf(s, 0.0f);
    }
    __syncthreads();

    if (tid < 128) {
        const int nn = tid >> 3, cls = tid & 7;
        float s = b2[cls];
        const float* wrow = W2 + cls * 64;
        const float* hrow = headL + nn * 64;
        #pragma unroll
        for (int k = 0; k < 64; k += 4) {
            const f32x4 hv = *(const f32x4*)&hrow[k];
            const f32x4 wv = *(const f32x4*)&wrow[k];
            s += hv[0]*wv[0] + hv[1]*wv[1] + hv[2]*wv[2] + hv[3]*wv[3];
        }
        out[(size_t)(b0 + nn) * 8 + cls] = s;
    }
#undef L0ITER
#undef L1ITER
}

extern "C" void kernel_launch(void* const* d_in, const int* in_sizes, int n_in,
                              void* d_out, int out_size, void* d_ws, size_t ws_size,
                              hipStream_t stream) {
    const float* x    = (const float*)d_in[0];
    const float* Wih0 = (const float*)d_in[1];
    const float* Whh0 = (const float*)d_in[2];
    const float* bih0 = (const float*)d_in[3];
    const float* bhh0 = (const float*)d_in[4];
    const float* Wih1 = (const float*)d_in[5];
    const float* Whh1 = (const float*)d_in[6];
    const float* bih1 = (const float*)d_in[7];
    const float* bhh1 = (const float*)d_in[8];
    const float* W1   = (const float*)d_in[9];
    const float* b1   = (const float*)d_in[10];
    const float* W2   = (const float*)d_in[11];
    const float* b2   = (const float*)d_in[12];
    float* outp = (float*)d_out;

    const size_t PACK_BYTES = (size_t)512 * 128 * sizeof(short);   // 128 KB

    if (ws_size >= PACK_BYTES) {
        short* wih1pk = (short*)d_ws;
        pack_wih1_kernel<<<8, 1024, 0, stream>>>(Wih1, wih1pk);
        lstm_mega_kernel<<<128, 1024, 0, stream>>>(
            x, Wih0, Whh0, bih0, bhh0, Whh1, bih1, bhh1,
            W1, b1, W2, b2, wih1pk, outp);
    } else {
        lstm_fused_kernel<<<128, 512, 0, stream>>>(
            x, Wih0, Whh0, bih0, bhh0, Wih1, Whh1, bih1, bhh1,
            W1, b1, W2, b2, outp);
    }
}